// Round 1
// baseline (856.490 us; speedup 1.0000x reference)
//
#include <hip/hip_runtime.h>
#include <hip/hip_bf16.h>
#include <math.h>

// ---------- types ----------
typedef __attribute__((ext_vector_type(8))) __bf16 bfrag;   // MFMA A/B operand (8 bf16, 4 VGPR)
typedef __attribute__((ext_vector_type(4))) float  f32x4;   // MFMA C/D
typedef __attribute__((ext_vector_type(8))) short  s16x8;
typedef __attribute__((ext_vector_type(4))) short  s16x4;

__device__ __forceinline__ short f2bf(float f) {
  return (short)__builtin_bit_cast(unsigned short, (__bf16)f);
}
__device__ __forceinline__ float bf2f(short s) {
  return (float)__builtin_bit_cast(__bf16, (unsigned short)s);
}

__device__ __forceinline__ void gll16(const void* g, void* l) {
  // async global->LDS, 16B/lane; LDS dest = wave-uniform base + lane*16
  __builtin_amdgcn_global_load_lds((const __attribute__((address_space(1))) void*)g,
                                   (__attribute__((address_space(3))) void*)l, 16, 0, 0);
}

// ---------- f32 -> bf16 convert (vectorized: float4 in, 4x bf16 out) ----------
__global__ __launch_bounds__(256) void cvt_f32_bf16(const float* __restrict__ in,
                                                    short* __restrict__ out, int n4) {
  int i = blockIdx.x * 256 + threadIdx.x;
  if (i >= n4) return;
  f32x4 v = ((const f32x4*)in)[i];
  s16x4 o;
  o.x = f2bf(v.x); o.y = f2bf(v.y); o.z = f2bf(v.z); o.w = f2bf(v.w);
  ((s16x4*)out)[i] = o;
}

// ---------- GEMM: C[M][N] = A[M][K] @ B[N][K]^T  (bf16 in, f32 acc) ----------
// m97 structure: 128x128 tile, BK=32, 4 waves (2x2), each wave 64x64 = 4x4 frags of 16x16x32.
template<bool BF16OUT>
__global__ __launch_bounds__(256) void gemm_bt(const short* __restrict__ A,
                                               const short* __restrict__ B,
                                               void* __restrict__ Cv,
                                               int M, int N, int K) {
  __shared__ short As[128 * 32];
  __shared__ short Bs[128 * 32];
  const int tid = threadIdx.x;
  const int lane = tid & 63, wid = tid >> 6;
  const int lg = lane >> 4, lr = lane & 15;
  const int bm = blockIdx.y << 7, bn = blockIdx.x << 7;
  const int wm = (wid >> 1) << 6, wn = (wid & 1) << 6;
  f32x4 acc[4][4] = {};
  for (int k0 = 0; k0 < K; k0 += 32) {
    __syncthreads();                      // protect LDS reuse (prev iter's reads done)
#pragma unroll
    for (int s = 0; s < 2; ++s) {
      const int c = s * 256 + tid;        // chunk: row=c>>2, 8-elem col chunk=c&3
      const int row = c >> 2, cc = (c & 3) << 3;
      gll16(A + (size_t)(bm + row) * K + k0 + cc,
            (char*)As + (size_t)(s * 256 + wid * 64) * 16);
      gll16(B + (size_t)(bn + row) * K + k0 + cc,
            (char*)Bs + (size_t)(s * 256 + wid * 64) * 16);
    }
    __syncthreads();                      // drains vmcnt(0): staged data visible
    bfrag af[4], bf_[4];
#pragma unroll
    for (int i = 0; i < 4; ++i) {
      af[i]  = *(const bfrag*)(As + (wm + i * 16 + lr) * 32 + lg * 8);
      bf_[i] = *(const bfrag*)(Bs + (wn + i * 16 + lr) * 32 + lg * 8);
    }
#pragma unroll
    for (int i = 0; i < 4; ++i)
#pragma unroll
      for (int j = 0; j < 4; ++j)
        acc[i][j] = __builtin_amdgcn_mfma_f32_16x16x32_bf16(af[i], bf_[j], acc[i][j], 0, 0, 0);
  }
  // C/D layout: col = lane&15 (B side), row = (lane>>4)*4 + reg (A side)
  const int rb = bm + wm + lg * 4, cb = bn + wn + lr;
#pragma unroll
  for (int i = 0; i < 4; ++i)
#pragma unroll
    for (int j = 0; j < 4; ++j)
#pragma unroll
      for (int r = 0; r < 4; ++r) {
        size_t idx = (size_t)(rb + i * 16 + r) * N + (cb + j * 16);
        if (BF16OUT) ((short*)Cv)[idx] = f2bf(acc[i][j][r]);
        else         ((float*)Cv)[idx] = acc[i][j][r];
      }
}

// ---------- RoPE in-place on QKV buffer (q heads 0..31, k heads 32..39; v untouched) ----------
__global__ __launch_bounds__(256) void rope_k(short* __restrict__ qkv,
                                              const float* __restrict__ fcos,
                                              const float* __restrict__ fsin) {
  const int t = blockIdx.x;          // token 0..4095 (b*2048 + s)
  const int s = t & 2047;
  unsigned* row = (unsigned*)(qkv + (size_t)t * 6144);
  for (int p = threadIdx.x; p < 2560; p += 256) {   // 40 heads * 64 pairs
    const int h = p >> 6, i = p & 63;
    const int w = h * 64 + i;                       // uint index == (h*128 + 2i)/2
    unsigned u = row[w];
    float a  = bf2f((short)(u & 0xffff));
    float b  = bf2f((short)(u >> 16));
    float c  = fcos[s * 64 + i], sn = fsin[s * 64 + i];
    float na = a * c - b * sn;
    float nb = a * sn + b * c;
    row[w] = ((unsigned)(unsigned short)f2bf(na)) |
             (((unsigned)(unsigned short)f2bf(nb)) << 16);
  }
}

// ---------- V transpose: qkv V-part [t][d] -> vt[b][kvh][d][s] ----------
__global__ __launch_bounds__(256) void vtrans(const short* __restrict__ qkv,
                                              short* __restrict__ vt) {
  const int sb = blockIdx.x, kvh = blockIdx.y, b = blockIdx.z;
  __shared__ short T[64][136];       // pad 128->136: 16B-aligned rows, 2-way-max banks on col reads
  const int tid = threadIdx.x;
#pragma unroll
  for (int it = 0; it < 4; ++it) {
    int c = it * 256 + tid;          // 1024 chunks: r=c>>4, 8-elem d chunk=c&15
    int r = c >> 4, dc = c & 15;
    s16x8 v = *(const s16x8*)(qkv + (size_t)(b * 2048 + sb * 64 + r) * 6144
                              + 5120 + kvh * 128 + dc * 8);
    *(s16x8*)&T[r][dc * 8] = v;
  }
  __syncthreads();
#pragma unroll
  for (int it = 0; it < 4; ++it) {
    int c = it * 256 + tid;          // d=c>>3, 8-elem s chunk=c&7
    int d = c >> 3, sc = c & 7;
    s16x8 v;
#pragma unroll
    for (int j = 0; j < 8; ++j) v[j] = T[sc * 8 + j][d];
    *(s16x8*)(vt + (size_t)((b * 8 + kvh) * 128 + d) * 2048 + sb * 64 + sc * 8) = v;
  }
}

// ---------- Flash attention: causal GQA, QBLK=64 (16 q-rows/wave), KVBLK=64 ----------
__global__ __launch_bounds__(256) void fattn(const short* __restrict__ qkv,
                                             const short* __restrict__ vt,
                                             short* __restrict__ ao) {
  const int qb = blockIdx.x, h = blockIdx.y, b = blockIdx.z;
  const int kvh = h >> 2;
  const int tid = threadIdx.x, lane = tid & 63, wid = tid >> 6;
  const int lg = lane >> 4, lr = lane & 15;
  __shared__ short Ks[64 * 128];     // [k][d], XOR-swizzled
  __shared__ short Vs[128 * 64];     // V^T [d][k], XOR-swizzled
  __shared__ short Ps[4][16 * 64];   // per-wave P [q][k], XOR-swizzled
  const int q0 = qb * 64 + wid * 16;
  // Q fragments hoisted to registers (A-frag: row=lr, k-chunk=lg)
  bfrag qf[4];
  {
    const short* qp = qkv + (size_t)(b * 2048 + q0 + lr) * 6144 + h * 128;
#pragma unroll
    for (int dc = 0; dc < 4; ++dc) qf[dc] = *(const bfrag*)(qp + dc * 32 + lg * 8);
  }
  f32x4 o[8] = {};                   // o[db]: q=(lg*4+r), d=db*16+lr
  float m_i[4], l_i[4];
#pragma unroll
  for (int r = 0; r < 4; ++r) { m_i[r] = -3.0e38f; l_i[r] = 0.f; }
  const float scale = 0.08838834764831845f;   // 1/sqrt(128)

  for (int t = 0; t <= qb; ++t) {
    __syncthreads();                 // prev tile's LDS reads done
#pragma unroll
    for (int it = 0; it < 4; ++it) {
      int c = it * 256 + tid;
      { // K tile [64][128]
        int kr = c >> 4, dc8 = c & 15;
        s16x8 v = *(const s16x8*)(qkv + (size_t)(b * 2048 + t * 64 + kr) * 6144
                                  + 4096 + kvh * 128 + dc8 * 8);
        *(s16x8*)((char*)Ks + ((kr * 256 + dc8 * 16) ^ ((kr & 7) << 4))) = v;
      }
      { // V^T tile [128][64]
        int d = c >> 3, kc = c & 7;
        s16x8 v = *(const s16x8*)(vt + (size_t)((b * 8 + kvh) * 128 + d) * 2048
                                  + t * 64 + kc * 8);
        *(s16x8*)((char*)Vs + ((d * 128 + kc * 16) ^ ((d & 7) << 4))) = v;
      }
    }
    __syncthreads();
    // S = Q K^T : D row=q(lg*4+r), col=k(nb*16+lr)
    f32x4 sres[4];
#pragma unroll
    for (int nb = 0; nb < 4; ++nb) {
      f32x4 s4 = {0.f, 0.f, 0.f, 0.f};
      const int kr = nb * 16 + lr;
#pragma unroll
      for (int dc = 0; dc < 4; ++dc) {
        bfrag kf = *(const bfrag*)((char*)Ks +
                     ((kr * 256 + dc * 64 + lg * 16) ^ ((kr & 7) << 4)));
        s4 = __builtin_amdgcn_mfma_f32_16x16x32_bf16(qf[dc], kf, s4, 0, 0, 0);
      }
      sres[nb] = s4;
    }
    // scale + causal mask + tile max
    float mt[4];
#pragma unroll
    for (int r = 0; r < 4; ++r) mt[r] = -3.0e38f;
    const bool diag = (t == qb);
#pragma unroll
    for (int nb = 0; nb < 4; ++nb) {
      const int kg = t * 64 + nb * 16 + lr;
#pragma unroll
      for (int r = 0; r < 4; ++r) {
        float v = sres[nb][r] * scale;
        if (diag && kg > q0 + lg * 4 + r) v = -3.0e38f;
        sres[nb][r] = v;
        mt[r] = fmaxf(mt[r], v);
      }
    }
#pragma unroll
    for (int r = 0; r < 4; ++r) {
#pragma unroll
      for (int dd = 1; dd < 16; dd <<= 1) mt[r] = fmaxf(mt[r], __shfl_xor(mt[r], dd, 64));
    }
    // online softmax update
    float fexp[4], psum[4];
#pragma unroll
    for (int r = 0; r < 4; ++r) {
      float nm = fmaxf(m_i[r], mt[r]);
      fexp[r] = __expf(m_i[r] - nm);   // first tile: exp(-3e38-nm)=0; no NaN possible
      m_i[r] = nm;
      psum[r] = 0.f;
    }
#pragma unroll
    for (int nb = 0; nb < 4; ++nb)
#pragma unroll
      for (int r = 0; r < 4; ++r) {
        float p = __expf(sres[nb][r] - m_i[r]);
        sres[nb][r] = p;
        psum[r] += p;
      }
#pragma unroll
    for (int r = 0; r < 4; ++r) {
#pragma unroll
      for (int dd = 1; dd < 16; dd <<= 1) psum[r] += __shfl_xor(psum[r], dd, 64);
      l_i[r] = l_i[r] * fexp[r] + psum[r];
    }
#pragma unroll
    for (int db = 0; db < 8; ++db)
#pragma unroll
      for (int r = 0; r < 4; ++r) o[db][r] *= fexp[r];
    // P -> LDS (bf16) in [q][k] layout, swizzled
#pragma unroll
    for (int nb = 0; nb < 4; ++nb)
#pragma unroll
      for (int r = 0; r < 4; ++r) {
        int q = lg * 4 + r, k = nb * 16 + lr;
        *(short*)((char*)&Ps[wid][0] + ((q * 128 + k * 2) ^ ((q & 7) << 4))) =
            f2bf(sres[nb][r]);
      }
    __syncthreads();   // make P visible to all lanes of the wave (uniform across waves)
    // O += P @ V : A=P[q][k], B=V^T[d][k]
#pragma unroll
    for (int ks = 0; ks < 2; ++ks) {
      bfrag pa = *(const bfrag*)((char*)&Ps[wid][0] +
                   ((lr * 128 + ks * 64 + lg * 16) ^ ((lr & 7) << 4)));
#pragma unroll
      for (int db = 0; db < 8; ++db) {
        const int d = db * 16 + lr;
        bfrag vf = *(const bfrag*)((char*)Vs +
                     ((d * 128 + ks * 64 + lg * 16) ^ ((d & 7) << 4)));
        o[db] = __builtin_amdgcn_mfma_f32_16x16x32_bf16(pa, vf, o[db], 0, 0, 0);
      }
    }
  }
  // epilogue: normalize + store [t][h*128+d] bf16
#pragma unroll
  for (int r = 0; r < 4; ++r) l_i[r] = 1.f / l_i[r];
  short* aop = ao + (size_t)(b * 2048 + q0 + lg * 4) * 4096 + h * 128 + lr;
#pragma unroll
  for (int db = 0; db < 8; ++db)
#pragma unroll
    for (int r = 0; r < 4; ++r)
      aop[(size_t)r * 4096 + db * 16] = f2bf(o[db][r] * l_i[r]);
}

// ---------- launch ----------
extern "C" void kernel_launch(void* const* d_in, const int* in_sizes, int n_in,
                              void* d_out, int out_size, void* d_ws, size_t ws_size,
                              hipStream_t stream) {
  const float* x  = (const float*)d_in[0];
  const float* wq = (const float*)d_in[1];
  const float* wk = (const float*)d_in[2];
  const float* wv = (const float*)d_in[3];
  const float* wo = (const float*)d_in[4];
  const float* fc = (const float*)d_in[7];
  const float* fs = (const float*)d_in[8];
  // cache_k/cache_v/mask/start_pos unused: start_pos=0, mask==causal, caches not returned

  char* ws = (char*)d_ws;
  short* xb    = (short*)(ws);                    // [4096][4096] bf16 (x);  reused as ao after gemm1
  short* ao    = xb;
  short* wqkvb = (short*)(ws + 33554432ull);      // [6144][4096] bf16 (wq|wk|wv); reused as wob
  short* wob   = wqkvb;
  short* qkv   = (short*)(ws + 83886080ull);      // [4096][6144] bf16
  short* vt    = (short*)(ws + 134217728ull);     // [2][8][128][2048] bf16
  // total ws use: 142,606,336 bytes

  cvt_f32_bf16<<<16384, 256, 0, stream>>>(x,  xb,                 4194304);
  cvt_f32_bf16<<<16384, 256, 0, stream>>>(wq, wqkvb,              4194304);
  cvt_f32_bf16<<< 4096, 256, 0, stream>>>(wk, wqkvb + 16777216,   1048576);
  cvt_f32_bf16<<< 4096, 256, 0, stream>>>(wv, wqkvb + 20971520,   1048576);
  gemm_bt<true ><<<dim3(48, 32), 256, 0, stream>>>(xb, wqkvb, qkv, 4096, 6144, 4096);
  rope_k<<<4096, 256, 0, stream>>>(qkv, fc, fs);
  vtrans<<<dim3(32, 8, 2), 256, 0, stream>>>(qkv, vt);
  fattn <<<dim3(32, 32, 2), 256, 0, stream>>>(qkv, vt, ao);
  cvt_f32_bf16<<<16384, 256, 0, stream>>>(wo, wob,                4194304);
  gemm_bt<false><<<dim3(32, 32), 256, 0, stream>>>(ao, wob, (float*)d_out, 4096, 4096, 4096);
}

// Round 2
// 706.650 us; speedup vs baseline: 1.2120x; 1.2120x over previous
//
#include <hip/hip_runtime.h>
#include <hip/hip_bf16.h>
#include <math.h>

// ---------- types ----------
typedef __attribute__((ext_vector_type(8)))  __bf16 bfrag;   // MFMA A/B operand (8 bf16)
typedef __attribute__((ext_vector_type(4)))  float  f32x4;
typedef __attribute__((ext_vector_type(16))) float  f32x16;  // 32x32 MFMA C/D
typedef __attribute__((ext_vector_type(8)))  short  s16x8;
typedef __attribute__((ext_vector_type(4)))  short  s16x4;
typedef __attribute__((ext_vector_type(2)))  unsigned u32x2;
typedef __attribute__((ext_vector_type(4)))  unsigned u32x4;

__device__ __forceinline__ short f2bf(float f) {
  return (short)__builtin_bit_cast(unsigned short, (__bf16)f);
}
__device__ __forceinline__ float bf2f(short s) {
  return (float)__builtin_bit_cast(__bf16, (unsigned short)s);
}
__device__ __forceinline__ unsigned cvtpk(float lo, float hi_) {
  unsigned r;
  asm("v_cvt_pk_bf16_f32 %0, %1, %2" : "=v"(r) : "v"(lo), "v"(hi_));
  return r;
}
__device__ __forceinline__ void gll16(const void* g, void* l) {
  __builtin_amdgcn_global_load_lds((const __attribute__((address_space(1))) void*)g,
                                   (__attribute__((address_space(3))) void*)l, 16, 0, 0);
}

// ---------- f32 -> bf16 convert ----------
__global__ __launch_bounds__(256) void cvt_f32_bf16(const float* __restrict__ in,
                                                    short* __restrict__ out, int n4) {
  int i = blockIdx.x * 256 + threadIdx.x;
  if (i >= n4) return;
  f32x4 v = ((const f32x4*)in)[i];
  s16x4 o;
  o.x = f2bf(v.x); o.y = f2bf(v.y); o.z = f2bf(v.z); o.w = f2bf(v.w);
  ((s16x4*)out)[i] = o;
}

// ---------- GEMM: C[M][N] = A[M][K] @ B[N][K]^T (m97 structure, unchanged) ----------
template<bool BF16OUT>
__global__ __launch_bounds__(256) void gemm_bt(const short* __restrict__ A,
                                               const short* __restrict__ B,
                                               void* __restrict__ Cv,
                                               int M, int N, int K) {
  __shared__ short As[128 * 32];
  __shared__ short Bs[128 * 32];
  const int tid = threadIdx.x;
  const int lane = tid & 63, wid = tid >> 6;
  const int lg = lane >> 4, lr = lane & 15;
  const int bm = blockIdx.y << 7, bn = blockIdx.x << 7;
  const int wm = (wid >> 1) << 6, wn = (wid & 1) << 6;
  f32x4 acc[4][4] = {};
  for (int k0 = 0; k0 < K; k0 += 32) {
    __syncthreads();
#pragma unroll
    for (int s = 0; s < 2; ++s) {
      const int c = s * 256 + tid;
      const int row = c >> 2, cc = (c & 3) << 3;
      gll16(A + (size_t)(bm + row) * K + k0 + cc,
            (char*)As + (size_t)(s * 256 + wid * 64) * 16);
      gll16(B + (size_t)(bn + row) * K + k0 + cc,
            (char*)Bs + (size_t)(s * 256 + wid * 64) * 16);
    }
    __syncthreads();
    bfrag af[4], bf_[4];
#pragma unroll
    for (int i = 0; i < 4; ++i) {
      af[i]  = *(const bfrag*)(As + (wm + i * 16 + lr) * 32 + lg * 8);
      bf_[i] = *(const bfrag*)(Bs + (wn + i * 16 + lr) * 32 + lg * 8);
    }
#pragma unroll
    for (int i = 0; i < 4; ++i)
#pragma unroll
      for (int j = 0; j < 4; ++j)
        acc[i][j] = __builtin_amdgcn_mfma_f32_16x16x32_bf16(af[i], bf_[j], acc[i][j], 0, 0, 0);
  }
  const int rb = bm + wm + lg * 4, cb = bn + wn + lr;
#pragma unroll
  for (int i = 0; i < 4; ++i)
#pragma unroll
    for (int j = 0; j < 4; ++j)
#pragma unroll
      for (int r = 0; r < 4; ++r) {
        size_t idx = (size_t)(rb + i * 16 + r) * N + (cb + j * 16);
        if (BF16OUT) ((short*)Cv)[idx] = f2bf(acc[i][j][r]);
        else         ((float*)Cv)[idx] = acc[i][j][r];
      }
}

// ---------- RoPE in-place (q heads 0..31, k heads 32..39) ----------
__global__ __launch_bounds__(256) void rope_k(short* __restrict__ qkv,
                                              const float* __restrict__ fcos,
                                              const float* __restrict__ fsin) {
  const int t = blockIdx.x;
  const int s = t & 2047;
  unsigned* row = (unsigned*)(qkv + (size_t)t * 6144);
  for (int p = threadIdx.x; p < 2560; p += 256) {
    const int h = p >> 6, i = p & 63;
    const int w = h * 64 + i;
    unsigned u = row[w];
    float a  = bf2f((short)(u & 0xffff));
    float b  = bf2f((short)(u >> 16));
    float c  = fcos[s * 64 + i], sn = fsin[s * 64 + i];
    float na = a * c - b * sn;
    float nb = a * sn + b * c;
    row[w] = ((unsigned)(unsigned short)f2bf(na)) |
             (((unsigned)(unsigned short)f2bf(nb)) << 16);
  }
}

// ---------- V transpose: qkv V-part [t][d] -> vt[b][kvh][d][s] ----------
__global__ __launch_bounds__(256) void vtrans(const short* __restrict__ qkv,
                                              short* __restrict__ vt) {
  const int sb = blockIdx.x, kvh = blockIdx.y, b = blockIdx.z;
  __shared__ short T[64][136];
  const int tid = threadIdx.x;
#pragma unroll
  for (int it = 0; it < 4; ++it) {
    int c = it * 256 + tid;
    int r = c >> 4, dc = c & 15;
    s16x8 v = *(const s16x8*)(qkv + (size_t)(b * 2048 + sb * 64 + r) * 6144
                              + 5120 + kvh * 128 + dc * 8);
    *(s16x8*)&T[r][dc * 8] = v;
  }
  __syncthreads();
#pragma unroll
  for (int it = 0; it < 4; ++it) {
    int c = it * 256 + tid;
    int d = c >> 3, sc = c & 7;
    s16x8 v;
#pragma unroll
    for (int j = 0; j < 8; ++j) v[j] = T[sc * 8 + j][d];
    *(s16x8*)(vt + (size_t)((b * 8 + kvh) * 128 + d) * 2048 + sb * 64 + sc * 8) = v;
  }
}

// ---------- Flash attention, m214 structure: 8 warps x 32 q-rows, 32x32x16 MFMA ----------
// Swapped QK^T (S^T = mfma(K,Q)): lane owns q = q0w + (lane&31); holds k = crow(r,hi).
// PV computes O^T = mfma(V^T, P^T) so m/l/rescale stay lane-local.
__global__ __launch_bounds__(512, 2) void fattn2(const short* __restrict__ qkv,
                                                 const short* __restrict__ vt,
                                                 short* __restrict__ ao) {
  const int qb = blockIdx.x, h = blockIdx.y, b = blockIdx.z;
  const int kvh = h >> 2;
  const int tid = threadIdx.x;
  const int lane = tid & 63, wid = tid >> 6;
  const int l31 = lane & 31, hi = lane >> 5;
  __shared__ __align__(16) short Ks[2][64 * 128];   // [k][d], XOR-swizzled
  __shared__ __align__(16) short Vs[2][128 * 64];   // V^T [d][k], XOR-swizzled

  const int q0w   = qb * 256 + wid * 32;
  const int qg    = q0w + l31;         // this lane's q row (global)
  const int tmaxw = q0w >> 6;          // last KV-tile this warp computes
  const int NT    = 4 * qb + 4;

  // Q as B-fragments: col q = l31, elems d = kk*16 + hi*8 + j
  bfrag qf[8];
  {
    const short* qp = qkv + (size_t)(b * 2048 + qg) * 6144 + h * 128 + hi * 8;
#pragma unroll
    for (int kk = 0; kk < 8; ++kk) qf[kk] = *(const bfrag*)(qp + kk * 16);
  }

  // staging: 512 threads, 2 x 16B K-chunks + 2 x 16B V-chunks each
  const int kr0 = tid >> 4, kcc = tid & 15;
  const int vd0 = tid >> 3, vkc = tid & 7;
  const int kro[2] = { kr0, kr0 + 32 };
  const int vdo[2] = { vd0, vd0 + 64 };
  int kldst[2], vldst[2];
#pragma unroll
  for (int i = 0; i < 2; ++i) {
    kldst[i] = (kro[i] * 256 + kcc * 16) ^ ((kro[i] & 7) << 4);
    vldst[i] = (vdo[i] * 128 + vkc * 16) ^ ((vdo[i] & 7) << 4);
  }
  const short* base_k = qkv + (size_t)(b * 2048) * 6144 + 4096 + kvh * 128;
  const short* base_v = vt + (size_t)((b * 8 + kvh) * 128) * 2048;

  { // prologue: stage tile 0 into buf 0
    s16x8 kr_[2], vr_[2];
#pragma unroll
    for (int i = 0; i < 2; ++i) {
      kr_[i] = *(const s16x8*)(base_k + (size_t)kro[i] * 6144 + kcc * 8);
      vr_[i] = *(const s16x8*)(base_v + (size_t)vdo[i] * 2048 + vkc * 8);
    }
#pragma unroll
    for (int i = 0; i < 2; ++i) {
      *(s16x8*)((char*)Ks[0] + kldst[i]) = kr_[i];
      *(s16x8*)((char*)Vs[0] + vldst[i]) = vr_[i];
    }
  }
  __syncthreads();

  f32x16 o[4] = {};                    // O^T: row d = dt*32+crow(r,hi), col q = l31
  float m = -3.0e38f, l = 0.f;
  const float c0 = 0.08838834764831845f * 1.4426950408889634f;  // scale * log2(e)
  const int  sw = (l31 & 7) << 4;

  for (int t = 0; t < NT; ++t) {
    const int cur = t & 1;
    // T14: issue next tile's global loads before compute
    s16x8 kr_[2], vr_[2];
    const bool pf = (t + 1 < NT);
    if (pf) {
#pragma unroll
      for (int i = 0; i < 2; ++i) {
        kr_[i] = *(const s16x8*)(base_k + (size_t)((t + 1) * 64 + kro[i]) * 6144 + kcc * 8);
        vr_[i] = *(const s16x8*)(base_v + (size_t)vdo[i] * 2048 + (t + 1) * 64 + vkc * 8);
      }
    }
    if (t <= tmaxw) {
      // ---- S^T = K @ Q : two 32x32 k-tiles ----
      f32x16 st[2];
      __builtin_amdgcn_s_setprio(1);
#pragma unroll
      for (int kt = 0; kt < 2; ++kt) {
        f32x16 acc = {};
        const char* kb = (const char*)Ks[cur] + kt * 8192 + l31 * 256;
#pragma unroll
        for (int kk = 0; kk < 8; ++kk) {
          bfrag kf = *(const bfrag*)(kb + ((kk * 32 + hi * 16) ^ sw));
          acc = __builtin_amdgcn_mfma_f32_32x32x16_bf16(kf, qf[kk], acc, 0, 0, 0);
        }
        st[kt] = acc;
      }
      __builtin_amdgcn_s_setprio(0);
      // ---- causal mask (diag tile only) + row max ----
      if (t == tmaxw) {
        const int kb0 = t * 64 + 4 * hi;
#pragma unroll
        for (int kt = 0; kt < 2; ++kt)
#pragma unroll
          for (int r = 0; r < 16; ++r) {
            int k = kb0 + kt * 32 + (r & 3) + 8 * (r >> 2);
            if (k > qg) st[kt][r] = -3.0e38f;
          }
      }
      float mt = -3.0e38f;
#pragma unroll
      for (int kt = 0; kt < 2; ++kt)
#pragma unroll
        for (int r = 0; r < 16; ++r) mt = fmaxf(mt, st[kt][r]);
      mt = fmaxf(mt, __shfl_xor(mt, 32, 64));
      // ---- defer-max (T13) online update ----
      if (!__all((mt - m) * c0 <= 8.0f)) {
        float nm = fmaxf(m, mt);
        float fe = exp2f((m - nm) * c0);
        m = nm;
        l *= fe;
#pragma unroll
        for (int dt = 0; dt < 4; ++dt)
#pragma unroll
          for (int r = 0; r < 16; ++r) o[dt][r] *= fe;
      }
      const float mc = m * c0;
      float ps = 0.f;
#pragma unroll
      for (int kt = 0; kt < 2; ++kt)
#pragma unroll
        for (int r = 0; r < 16; ++r) {
          float p = exp2f(st[kt][r] * c0 - mc);
          st[kt][r] = p;
          ps += p;
        }
      ps += __shfl_xor(ps, 32, 64);
      l += ps;
      // ---- T12: pack P to PV B-fragments in-register (cvt_pk + permlane32_swap) ----
      bfrag pfr[4];
#pragma unroll
      for (int kt = 0; kt < 2; ++kt) {
        u32x2 a0 = __builtin_amdgcn_permlane32_swap(cvtpk(st[kt][0],  st[kt][1]),
                                                    cvtpk(st[kt][4],  st[kt][5]),  0, 0);
        u32x2 a1 = __builtin_amdgcn_permlane32_swap(cvtpk(st[kt][2],  st[kt][3]),
                                                    cvtpk(st[kt][6],  st[kt][7]),  0, 0);
        u32x2 b0 = __builtin_amdgcn_permlane32_swap(cvtpk(st[kt][8],  st[kt][9]),
                                                    cvtpk(st[kt][12], st[kt][13]), 0, 0);
        u32x2 b1 = __builtin_amdgcn_permlane32_swap(cvtpk(st[kt][10], st[kt][11]),
                                                    cvtpk(st[kt][14], st[kt][15]), 0, 0);
        u32x4 w0 = { a0.x, a1.x, a0.y, a1.y };
        u32x4 w1 = { b0.x, b1.x, b0.y, b1.y };
        pfr[kt * 2]     = __builtin_bit_cast(bfrag, w0);
        pfr[kt * 2 + 1] = __builtin_bit_cast(bfrag, w1);
      }
      // ---- O^T += V^T @ P^T ----
      __builtin_amdgcn_s_setprio(1);
#pragma unroll
      for (int ks = 0; ks < 4; ++ks) {
        const char* vb = (const char*)Vs[cur] + l31 * 128 + ((ks * 32 + hi * 16) ^ sw);
#pragma unroll
        for (int dt = 0; dt < 4; ++dt) {
          bfrag vf = *(const bfrag*)(vb + dt * 4096);
          o[dt] = __builtin_amdgcn_mfma_f32_32x32x16_bf16(vf, pfr[ks], o[dt], 0, 0, 0);
        }
      }
      __builtin_amdgcn_s_setprio(0);
    }
    __syncthreads();                  // all reads of buf[cur^1] (iter t-1) + buf[cur] done
    if (pf) {
#pragma unroll
      for (int i = 0; i < 2; ++i) {
        *(s16x8*)((char*)Ks[cur ^ 1] + kldst[i]) = kr_[i];
        *(s16x8*)((char*)Vs[cur ^ 1] + vldst[i]) = vr_[i];
      }
    }
    __syncthreads();                  // staged tile visible
  }
  // ---- epilogue: normalize, store O[q][d] ----
  const float linv = 1.f / l;
  short* aop = ao + (size_t)(b * 2048 + qg) * 4096 + h * 128 + 4 * hi;
#pragma unroll
  for (int dt = 0; dt < 4; ++dt)
#pragma unroll
    for (int r = 0; r < 16; ++r) {
      int d = dt * 32 + (r & 3) + 8 * (r >> 2);
      aop[d] = f2bf(o[dt][r] * linv);
    }
}

// ---------- launch ----------
extern "C" void kernel_launch(void* const* d_in, const int* in_sizes, int n_in,
                              void* d_out, int out_size, void* d_ws, size_t ws_size,
                              hipStream_t stream) {
  const float* x  = (const float*)d_in[0];
  const float* wq = (const float*)d_in[1];
  const float* wk = (const float*)d_in[2];
  const float* wv = (const float*)d_in[3];
  const float* wo = (const float*)d_in[4];
  const float* fc = (const float*)d_in[7];
  const float* fs = (const float*)d_in[8];

  char* ws = (char*)d_ws;
  short* xb    = (short*)(ws);                    // [4096][4096] bf16; reused as ao
  short* ao    = xb;
  short* wqkvb = (short*)(ws + 33554432ull);      // [6144][4096] bf16; reused as wob
  short* wob   = wqkvb;
  short* qkv   = (short*)(ws + 83886080ull);      // [4096][6144] bf16
  short* vt    = (short*)(ws + 134217728ull);     // [2][8][128][2048] bf16

  cvt_f32_bf16<<<16384, 256, 0, stream>>>(x,  xb,                 4194304);
  cvt_f32_bf16<<<16384, 256, 0, stream>>>(wq, wqkvb,              4194304);
  cvt_f32_bf16<<< 4096, 256, 0, stream>>>(wk, wqkvb + 16777216,   1048576);
  cvt_f32_bf16<<< 4096, 256, 0, stream>>>(wv, wqkvb + 20971520,   1048576);
  gemm_bt<true ><<<dim3(48, 32), 256, 0, stream>>>(xb, wqkvb, qkv, 4096, 6144, 4096);
  rope_k<<<4096, 256, 0, stream>>>(qkv, fc, fs);
  vtrans<<<dim3(32, 8, 2), 256, 0, stream>>>(qkv, vt);
  fattn2<<<dim3(8, 32, 2), 512, 0, stream>>>(qkv, vt, ao);
  cvt_f32_bf16<<<16384, 256, 0, stream>>>(wo, wob,                4194304);
  gemm_bt<false><<<dim3(32, 32), 256, 0, stream>>>(ao, wob, (float*)d_out, 4096, 4096, 4096);
}

// Round 3
// 620.758 us; speedup vs baseline: 1.3797x; 1.1384x over previous
//
#include <hip/hip_runtime.h>
#include <hip/hip_bf16.h>
#include <math.h>

// ---------- types ----------
typedef __attribute__((ext_vector_type(8)))  __bf16 bfrag;   // MFMA A/B operand (8 bf16)
typedef __attribute__((ext_vector_type(4)))  float  f32x4;
typedef __attribute__((ext_vector_type(16))) float  f32x16;  // 32x32 MFMA C/D
typedef __attribute__((ext_vector_type(8)))  short  s16x8;
typedef __attribute__((ext_vector_type(4)))  short  s16x4;
typedef __attribute__((ext_vector_type(2)))  unsigned u32x2;
typedef __attribute__((ext_vector_type(4)))  unsigned u32x4;

__device__ __forceinline__ short f2bf(float f) {
  return (short)__builtin_bit_cast(unsigned short, (__bf16)f);
}
__device__ __forceinline__ float bf2f(short s) {
  return (float)__builtin_bit_cast(__bf16, (unsigned short)s);
}
__device__ __forceinline__ unsigned cvtpk(float lo, float hi_) {
  unsigned r;
  asm("v_cvt_pk_bf16_f32 %0, %1, %2" : "=v"(r) : "v"(lo), "v"(hi_));
  return r;
}
__device__ __forceinline__ void gll16(const void* g, void* l) {
  __builtin_amdgcn_global_load_lds((const __attribute__((address_space(1))) void*)g,
                                   (__attribute__((address_space(3))) void*)l, 16, 0, 0);
}

// ---------- f32 -> bf16 convert ----------
__global__ __launch_bounds__(256) void cvt_f32_bf16(const float* __restrict__ in,
                                                    short* __restrict__ out, int n4) {
  int i = blockIdx.x * 256 + threadIdx.x;
  if (i >= n4) return;
  f32x4 v = ((const f32x4*)in)[i];
  s16x4 o;
  o.x = f2bf(v.x); o.y = f2bf(v.y); o.z = f2bf(v.z); o.w = f2bf(v.w);
  ((s16x4*)out)[i] = o;
}

// ---------- GEMM 256x256 tile, BK=32, ring-4 LDS pipeline (T1..T5) ----------
// C[M][N] = A[M][K] @ B[N][K]^T, bf16 in, f32 acc.
// 8 waves (2M x 4N), per-wave 128x64 output = acc[8][4] of 16x16 frags.
// Ring of 4 K-tile buffers; stage tile t+3 while computing t; counted vmcnt(8)
// once per K-tile (tile t+1 guaranteed landed; t+2,t+3 stay in flight).
// LDS swizzle: 16B-chunk XOR (chunk ^= (row>>1)&3) -> 2-way residual conflict.
// Staged via global_load_lds (linear LDS dest) with inverse-swizzled global src.
template<bool BF16OUT>
__global__ __launch_bounds__(512) void gemm256(const short* __restrict__ A,
                                               const short* __restrict__ B,
                                               void* __restrict__ Cv,
                                               int M, int N, int K, int NBX) {
  __shared__ __align__(16) short As[4][256 * 32];   // 4 x 16 KB
  __shared__ __align__(16) short Bs[4][256 * 32];   // 4 x 16 KB  (total 128 KB)
  const int tid = threadIdx.x, lane = tid & 63, wid = tid >> 6;
  const int lr = lane & 15, lg = lane >> 4;
  const int wm = wid >> 2, wn = wid & 3;
  // bijective XCD-aware block swizzle (m204)
  const int nwg = gridDim.x, orig = blockIdx.x;
  const int qq = nwg >> 3, rr = nwg & 7, xc = orig & 7, o8 = orig >> 3;
  const int wg = (xc < rr ? xc * (qq + 1) : rr * (qq + 1) + (xc - rr) * qq) + o8;
  const int bm = (wg / NBX) << 8, bn = (wg % NBX) << 8;
  const int NT = K >> 5;
  // staging: wave wid stages rows [wid*32, wid*32+32) of each tile (2 gll16 of 1024B)
  const int srow   = lane >> 2;                      // row within 16-row stripe
  const int schunk = (lane & 3) ^ ((lane >> 3) & 3); // inverse-swizzled 16B chunk
  // ds_read chunk swizzle: row = ...16*i + lr -> (row>>1)&3 == (lr>>1)&3
  const int rsw = ((lg ^ ((lr >> 1) & 3)) << 4);

  // ---- prologue: stage tiles 0,1,2 ----
  for (int pt = 0; pt < 3; ++pt) {
    const int k0 = pt * 32;
#pragma unroll
    for (int sti = 0; sti < 2; ++sti) {
      const int row = wid * 32 + sti * 16;
      gll16(A + (size_t)(bm + row + srow) * K + k0 + schunk * 8,
            (char*)As[pt] + row * 64);
    }
#pragma unroll
    for (int sti = 0; sti < 2; ++sti) {
      const int row = wid * 32 + sti * 16;
      gll16(B + (size_t)(bn + row + srow) * K + k0 + schunk * 8,
            (char*)Bs[pt] + row * 64);
    }
  }
  asm volatile("s_waitcnt vmcnt(8)" ::: "memory");   // tile 0 landed
  __builtin_amdgcn_s_barrier();

  f32x4 acc[8][4] = {};
  for (int t = 0; t < NT; ++t) {
    const int p = t & 3;
    int tf = t + 3; if (tf >= NT) tf -= NT;          // wrap: keeps vmcnt counts uniform
    const int bufs = (t + 3) & 3;                    // != p, p+1, p+2 (mod 4)
    const int k0f = tf * 32;
    const char* Ab = (const char*)As[p] + (size_t)(wm * 128 + lr) * 64 + rsw;
    const char* Bb = (const char*)Bs[p] + (size_t)(wn * 64  + lr) * 64 + rsw;
    // ---------- phase 1: i=0..3 ----------
    bfrag a_[4], b_[4];
#pragma unroll
    for (int i = 0; i < 4; ++i) a_[i] = *(const bfrag*)(Ab + i * 1024);
#pragma unroll
    for (int j = 0; j < 4; ++j) b_[j] = *(const bfrag*)(Bb + j * 1024);
#pragma unroll
    for (int sti = 0; sti < 2; ++sti) {              // stage A(t+3)
      const int row = wid * 32 + sti * 16;
      gll16(A + (size_t)(bm + row + srow) * K + k0f + schunk * 8,
            (char*)As[bufs] + row * 64);
    }
    __builtin_amdgcn_s_barrier();
    asm volatile("s_waitcnt lgkmcnt(0)" ::: "memory");
    __builtin_amdgcn_s_setprio(1);
#pragma unroll
    for (int i = 0; i < 4; ++i)
#pragma unroll
      for (int j = 0; j < 4; ++j)
        acc[i][j] = __builtin_amdgcn_mfma_f32_16x16x32_bf16(a_[i], b_[j], acc[i][j], 0, 0, 0);
    __builtin_amdgcn_s_setprio(0);
    __builtin_amdgcn_s_barrier();
    // ---------- phase 2: i=4..7 (B frags reused from registers) ----------
    bfrag a2_[4];
#pragma unroll
    for (int i = 0; i < 4; ++i) a2_[i] = *(const bfrag*)(Ab + (i + 4) * 1024);
#pragma unroll
    for (int sti = 0; sti < 2; ++sti) {              // stage B(t+3)
      const int row = wid * 32 + sti * 16;
      gll16(B + (size_t)(bn + row + srow) * K + k0f + schunk * 8,
            (char*)Bs[bufs] + row * 64);
    }
    __builtin_amdgcn_s_barrier();
    asm volatile("s_waitcnt lgkmcnt(0)" ::: "memory");
    __builtin_amdgcn_s_setprio(1);
#pragma unroll
    for (int i = 0; i < 4; ++i)
#pragma unroll
      for (int j = 0; j < 4; ++j)
        acc[i + 4][j] = __builtin_amdgcn_mfma_f32_16x16x32_bf16(a2_[i], b_[j], acc[i + 4][j], 0, 0, 0);
    __builtin_amdgcn_s_setprio(0);
    asm volatile("s_waitcnt vmcnt(8)" ::: "memory"); // tile t+1 landed; t+2,t+3 in flight
    __builtin_amdgcn_s_barrier();
  }
  // ---- epilogue ----
  const int rb = bm + wm * 128 + lg * 4, cb = bn + wn * 64 + lr;
#pragma unroll
  for (int i = 0; i < 8; ++i)
#pragma unroll
    for (int j = 0; j < 4; ++j)
#pragma unroll
      for (int r = 0; r < 4; ++r) {
        size_t idx = (size_t)(rb + i * 16 + r) * N + (cb + j * 16);
        if (BF16OUT) ((short*)Cv)[idx] = f2bf(acc[i][j][r]);
        else         ((float*)Cv)[idx] = acc[i][j][r];
      }
}

// ---------- RoPE in-place (q heads 0..31, k heads 32..39) ----------
__global__ __launch_bounds__(256) void rope_k(short* __restrict__ qkv,
                                              const float* __restrict__ fcos,
                                              const float* __restrict__ fsin) {
  const int t = blockIdx.x;
  const int s = t & 2047;
  unsigned* row = (unsigned*)(qkv + (size_t)t * 6144);
  for (int p = threadIdx.x; p < 2560; p += 256) {
    const int h = p >> 6, i = p & 63;
    const int w = h * 64 + i;
    unsigned u = row[w];
    float a  = bf2f((short)(u & 0xffff));
    float b  = bf2f((short)(u >> 16));
    float c  = fcos[s * 64 + i], sn = fsin[s * 64 + i];
    float na = a * c - b * sn;
    float nb = a * sn + b * c;
    row[w] = ((unsigned)(unsigned short)f2bf(na)) |
             (((unsigned)(unsigned short)f2bf(nb)) << 16);
  }
}

// ---------- V transpose: qkv V-part [t][d] -> vt[b][kvh][d][s] ----------
__global__ __launch_bounds__(256) void vtrans(const short* __restrict__ qkv,
                                              short* __restrict__ vt) {
  const int sb = blockIdx.x, kvh = blockIdx.y, b = blockIdx.z;
  __shared__ short T[64][136];
  const int tid = threadIdx.x;
#pragma unroll
  for (int it = 0; it < 4; ++it) {
    int c = it * 256 + tid;
    int r = c >> 4, dc = c & 15;
    s16x8 v = *(const s16x8*)(qkv + (size_t)(b * 2048 + sb * 64 + r) * 6144
                              + 5120 + kvh * 128 + dc * 8);
    *(s16x8*)&T[r][dc * 8] = v;
  }
  __syncthreads();
#pragma unroll
  for (int it = 0; it < 4; ++it) {
    int c = it * 256 + tid;
    int d = c >> 3, sc = c & 7;
    s16x8 v;
#pragma unroll
    for (int j = 0; j < 8; ++j) v[j] = T[sc * 8 + j][d];
    *(s16x8*)(vt + (size_t)((b * 8 + kvh) * 128 + d) * 2048 + sb * 64 + sc * 8) = v;
  }
}

// ---------- Flash attention, m214 structure (unchanged from round 2) ----------
__global__ __launch_bounds__(512, 2) void fattn2(const short* __restrict__ qkv,
                                                 const short* __restrict__ vt,
                                                 short* __restrict__ ao) {
  const int qb = blockIdx.x, h = blockIdx.y, b = blockIdx.z;
  const int kvh = h >> 2;
  const int tid = threadIdx.x;
  const int lane = tid & 63, wid = tid >> 6;
  const int l31 = lane & 31, hi = lane >> 5;
  __shared__ __align__(16) short Ks[2][64 * 128];
  __shared__ __align__(16) short Vs[2][128 * 64];

  const int q0w   = qb * 256 + wid * 32;
  const int qg    = q0w + l31;
  const int tmaxw = q0w >> 6;
  const int NT    = 4 * qb + 4;

  bfrag qf[8];
  {
    const short* qp = qkv + (size_t)(b * 2048 + qg) * 6144 + h * 128 + hi * 8;
#pragma unroll
    for (int kk = 0; kk < 8; ++kk) qf[kk] = *(const bfrag*)(qp + kk * 16);
  }

  const int kr0 = tid >> 4, kcc = tid & 15;
  const int vd0 = tid >> 3, vkc = tid & 7;
  const int kro[2] = { kr0, kr0 + 32 };
  const int vdo[2] = { vd0, vd0 + 64 };
  int kldst[2], vldst[2];
#pragma unroll
  for (int i = 0; i < 2; ++i) {
    kldst[i] = (kro[i] * 256 + kcc * 16) ^ ((kro[i] & 7) << 4);
    vldst[i] = (vdo[i] * 128 + vkc * 16) ^ ((vdo[i] & 7) << 4);
  }
  const short* base_k = qkv + (size_t)(b * 2048) * 6144 + 4096 + kvh * 128;
  const short* base_v = vt + (size_t)((b * 8 + kvh) * 128) * 2048;

  {
    s16x8 kr_[2], vr_[2];
#pragma unroll
    for (int i = 0; i < 2; ++i) {
      kr_[i] = *(const s16x8*)(base_k + (size_t)kro[i] * 6144 + kcc * 8);
      vr_[i] = *(const s16x8*)(base_v + (size_t)vdo[i] * 2048 + vkc * 8);
    }
#pragma unroll
    for (int i = 0; i < 2; ++i) {
      *(s16x8*)((char*)Ks[0] + kldst[i]) = kr_[i];
      *(s16x8*)((char*)Vs[0] + vldst[i]) = vr_[i];
    }
  }
  __syncthreads();

  f32x16 o[4] = {};
  float m = -3.0e38f, l = 0.f;
  const float c0 = 0.08838834764831845f * 1.4426950408889634f;
  const int  sw = (l31 & 7) << 4;

  for (int t = 0; t < NT; ++t) {
    const int cur = t & 1;
    s16x8 kr_[2], vr_[2];
    const bool pf = (t + 1 < NT);
    if (pf) {
#pragma unroll
      for (int i = 0; i < 2; ++i) {
        kr_[i] = *(const s16x8*)(base_k + (size_t)((t + 1) * 64 + kro[i]) * 6144 + kcc * 8);
        vr_[i] = *(const s16x8*)(base_v + (size_t)vdo[i] * 2048 + (t + 1) * 64 + vkc * 8);
      }
    }
    if (t <= tmaxw) {
      f32x16 st[2];
      __builtin_amdgcn_s_setprio(1);
#pragma unroll
      for (int kt = 0; kt < 2; ++kt) {
        f32x16 acc = {};
        const char* kb = (const char*)Ks[cur] + kt * 8192 + l31 * 256;
#pragma unroll
        for (int kk = 0; kk < 8; ++kk) {
          bfrag kf = *(const bfrag*)(kb + ((kk * 32 + hi * 16) ^ sw));
          acc = __builtin_amdgcn_mfma_f32_32x32x16_bf16(kf, qf[kk], acc, 0, 0, 0);
        }
        st[kt] = acc;
      }
      __builtin_amdgcn_s_setprio(0);
      if (t == tmaxw) {
        const int kb0 = t * 64 + 4 * hi;
#pragma unroll
        for (int kt = 0; kt < 2; ++kt)
#pragma unroll
          for (int r = 0; r < 16; ++r) {
            int k = kb0 + kt * 32 + (r & 3) + 8 * (r >> 2);
            if (k > qg) st[kt][r] = -3.0e38f;
          }
      }
      float mt = -3.0e38f;
#pragma unroll
      for (int kt = 0; kt < 2; ++kt)
#pragma unroll
        for (int r = 0; r < 16; ++r) mt = fmaxf(mt, st[kt][r]);
      mt = fmaxf(mt, __shfl_xor(mt, 32, 64));
      if (!__all((mt - m) * c0 <= 8.0f)) {
        float nm = fmaxf(m, mt);
        float fe = exp2f((m - nm) * c0);
        m = nm;
        l *= fe;
#pragma unroll
        for (int dt = 0; dt < 4; ++dt)
#pragma unroll
          for (int r = 0; r < 16; ++r) o[dt][r] *= fe;
      }
      const float mc = m * c0;
      float ps = 0.f;
#pragma unroll
      for (int kt = 0; kt < 2; ++kt)
#pragma unroll
        for (int r = 0; r < 16; ++r) {
          float p = exp2f(st[kt][r] * c0 - mc);
          st[kt][r] = p;
          ps += p;
        }
      ps += __shfl_xor(ps, 32, 64);
      l += ps;
      bfrag pfr[4];
#pragma unroll
      for (int kt = 0; kt < 2; ++kt) {
        u32x2 a0 = __builtin_amdgcn_permlane32_swap(cvtpk(st[kt][0],  st[kt][1]),
                                                    cvtpk(st[kt][4],  st[kt][5]),  0, 0);
        u32x2 a1 = __builtin_amdgcn_permlane32_swap(cvtpk(st[kt][2],  st[kt][3]),
                                                    cvtpk(st[kt][6],  st[kt][7]),  0, 0);
        u32x2 b0 = __builtin_amdgcn_permlane32_swap(cvtpk(st[kt][8],  st[kt][9]),
                                                    cvtpk(st[kt][12], st[kt][13]), 0, 0);
        u32x2 b1 = __builtin_amdgcn_permlane32_swap(cvtpk(st[kt][10], st[kt][11]),
                                                    cvtpk(st[kt][14], st[kt][15]), 0, 0);
        u32x4 w0 = { a0.x, a1.x, a0.y, a1.y };
        u32x4 w1 = { b0.x, b1.x, b0.y, b1.y };
        pfr[kt * 2]     = __builtin_bit_cast(bfrag, w0);
        pfr[kt * 2 + 1] = __builtin_bit_cast(bfrag, w1);
      }
      __builtin_amdgcn_s_setprio(1);
#pragma unroll
      for (int ks = 0; ks < 4; ++ks) {
        const char* vb = (const char*)Vs[cur] + l31 * 128 + ((ks * 32 + hi * 16) ^ sw);
#pragma unroll
        for (int dt = 0; dt < 4; ++dt) {
          bfrag vf = *(const bfrag*)(vb + dt * 4096);
          o[dt] = __builtin_amdgcn_mfma_f32_32x32x16_bf16(vf, pfr[ks], o[dt], 0, 0, 0);
        }
      }
      __builtin_amdgcn_s_setprio(0);
    }
    __syncthreads();
    if (pf) {
#pragma unroll
      for (int i = 0; i < 2; ++i) {
        *(s16x8*)((char*)Ks[cur ^ 1] + kldst[i]) = kr_[i];
        *(s16x8*)((char*)Vs[cur ^ 1] + vldst[i]) = vr_[i];
      }
    }
    __syncthreads();
  }
  const float linv = 1.f / l;
  short* aop = ao + (size_t)(b * 2048 + qg) * 4096 + h * 128 + 4 * hi;
#pragma unroll
  for (int dt = 0; dt < 4; ++dt)
#pragma unroll
    for (int r = 0; r < 16; ++r) {
      int d = dt * 32 + (r & 3) + 8 * (r >> 2);
      aop[d] = f2bf(o[dt][r] * linv);
    }
}

// ---------- launch ----------
extern "C" void kernel_launch(void* const* d_in, const int* in_sizes, int n_in,
                              void* d_out, int out_size, void* d_ws, size_t ws_size,
                              hipStream_t stream) {
  const float* x  = (const float*)d_in[0];
  const float* wq = (const float*)d_in[1];
  const float* wk = (const float*)d_in[2];
  const float* wv = (const float*)d_in[3];
  const float* wo = (const float*)d_in[4];
  const float* fc = (const float*)d_in[7];
  const float* fs = (const float*)d_in[8];

  char* ws = (char*)d_ws;
  short* xb    = (short*)(ws);                    // [4096][4096] bf16; reused as ao
  short* ao    = xb;
  short* wqkvb = (short*)(ws + 33554432ull);      // [6144][4096] bf16; reused as wob
  short* wob   = wqkvb;
  short* qkv   = (short*)(ws + 83886080ull);      // [4096][6144] bf16
  short* vt    = (short*)(ws + 134217728ull);     // [2][8][128][2048] bf16

  cvt_f32_bf16<<<16384, 256, 0, stream>>>(x,  xb,                 4194304);
  cvt_f32_bf16<<<16384, 256, 0, stream>>>(wq, wqkvb,              4194304);
  cvt_f32_bf16<<< 4096, 256, 0, stream>>>(wk, wqkvb + 16777216,   1048576);
  cvt_f32_bf16<<< 4096, 256, 0, stream>>>(wv, wqkvb + 20971520,   1048576);
  gemm256<true ><<<384, 512, 0, stream>>>(xb, wqkvb, qkv, 4096, 6144, 4096, 24);
  rope_k<<<4096, 256, 0, stream>>>(qkv, fc, fs);
  vtrans<<<dim3(32, 8, 2), 256, 0, stream>>>(qkv, vt);
  fattn2<<<dim3(8, 32, 2), 512, 0, stream>>>(qkv, vt, ao);
  cvt_f32_bf16<<<16384, 256, 0, stream>>>(wo, wob,                4194304);
  gemm256<false><<<256, 512, 0, stream>>>(ao, wob, (float*)d_out, 4096, 4096, 4096, 16);
}

// Round 4
// 608.991 us; speedup vs baseline: 1.4064x; 1.0193x over previous
//
#include <hip/hip_runtime.h>
#include <hip/hip_bf16.h>
#include <math.h>

// ---------- types ----------
typedef __attribute__((ext_vector_type(8)))  __bf16 bfrag;   // MFMA A/B operand (8 bf16)
typedef __attribute__((ext_vector_type(4)))  float  f32x4;
typedef __attribute__((ext_vector_type(16))) float  f32x16;  // 32x32 MFMA C/D
typedef __attribute__((ext_vector_type(8)))  short  s16x8;
typedef __attribute__((ext_vector_type(4)))  short  s16x4;
typedef __attribute__((ext_vector_type(2)))  unsigned u32x2;
typedef __attribute__((ext_vector_type(4)))  unsigned u32x4;

__device__ __forceinline__ short f2bf(float f) {
  return (short)__builtin_bit_cast(unsigned short, (__bf16)f);
}
__device__ __forceinline__ float bf2f(short s) {
  return (float)__builtin_bit_cast(__bf16, (unsigned short)s);
}
__device__ __forceinline__ unsigned cvtpk(float lo, float hi_) {
  unsigned r;
  asm("v_cvt_pk_bf16_f32 %0, %1, %2" : "=v"(r) : "v"(lo), "v"(hi_));
  return r;
}
__device__ __forceinline__ void gll16(const void* g, void* l) {
  __builtin_amdgcn_global_load_lds((const __attribute__((address_space(1))) void*)g,
                                   (__attribute__((address_space(3))) void*)l, 16, 0, 0);
}

// ---------- f32 -> bf16 convert ----------
__global__ __launch_bounds__(256) void cvt_f32_bf16(const float* __restrict__ in,
                                                    short* __restrict__ out, int n4) {
  int i = blockIdx.x * 256 + threadIdx.x;
  if (i >= n4) return;
  f32x4 v = ((const f32x4*)in)[i];
  s16x4 o;
  o.x = f2bf(v.x); o.y = f2bf(v.y); o.z = f2bf(v.z); o.w = f2bf(v.w);
  ((s16x4*)out)[i] = o;
}

// ---------- GEMM 256x256, BK=64, m201 8-phase schedule ----------
// C[M][N] = A[M][K] @ B[N][K]^T, bf16 in, f32 acc.
// 8 waves (2M x 4N); per-wave 128x64 = acc[8][4] of 16x16 frags.
// 2 LDS buffers (one K-tile of A+B each), alternating per K-tile (kt&1).
// 4 phases per K-tile: quad order (A0,B0),(A0,B1),(A1,B1),(A1,B0); 16 MFMA each.
// Stage slots (1 half-tile = 2 gll16 each): p0->A1(kt+1), p1->B0(kt+1),
//   p2->A0(kt+2), p3->B1(kt+2); counted vmcnt(4) at each p3 end drains kt+1 fully.
// LDS swizzle: 16B chunk c of row r stored at c^(r&7); stage source pre-swizzled.
template<bool BF16OUT>
__global__ __launch_bounds__(512) void gemm256(const short* __restrict__ A,
                                               const short* __restrict__ B,
                                               void* __restrict__ Cv,
                                               int M, int N, int K, int NBX) {
  __shared__ __align__(16) short As[2][256 * 64];   // 2 x 32 KB
  __shared__ __align__(16) short Bs[2][256 * 64];   // 2 x 32 KB (total 128 KB)
  const int tid = threadIdx.x, lane = tid & 63, wid = tid >> 6;
  const int lr = lane & 15, lg = lane >> 4;
  const int wm = wid >> 2, wn = wid & 3;
  // bijective XCD-aware block swizzle (m204)
  const int nwg = gridDim.x, orig = blockIdx.x;
  const int qq = nwg >> 3, rr = nwg & 7, xc = orig & 7, o8 = orig >> 3;
  const int wg = (xc < rr ? xc * (qq + 1) : rr * (qq + 1) + (xc - rr) * qq) + o8;
  const int bm = (wg / NBX) << 8, bn = (wg % NBX) << 8;
  const int NT = K >> 6;
  // staging thread mapping: half-tile = 128 rows x 64 cols; id = s*512+tid
  const int r0 = tid >> 3;                 // row within 64-row stripe
  const int c0 = tid & 7;
  const int csrc = c0 ^ (r0 & 7);          // inverse-swizzled 16B source chunk

#define STG(OP, OPs, boff, bb, hh, kt_)                                          \
  do {                                                                           \
    _Pragma("unroll")                                                            \
    for (int s = 0; s < 2; ++s)                                                  \
      gll16(OP + (size_t)(boff + (hh) * 128 + s * 64 + r0) * K + (kt_) * 64 + csrc * 8, \
            (char*)OPs[bb] + ((hh) * 128 + s * 64 + wid * 8) * 128);             \
  } while (0)

  // ds_read swizzled chunk offsets: element chunk (ks*4+lg) ^ (lr&7), x16 bytes
  int ch[2];
#pragma unroll
  for (int ks = 0; ks < 2; ++ks) ch[ks] = (((ks << 2) | lg) ^ (lr & 7)) << 4;
  const int aoff = (wm * 128 + lr) * 128;
  const int boff_ = (wn * 64 + lr) * 128;

  // ---- prologue: kt0 full (A0,B0,A1,B1) into buf0; A0(1),B1(1) into buf1 ----
  STG(A, As, bm, 0, 0, 0); STG(B, Bs, bn, 0, 0, 0);
  STG(A, As, bm, 0, 1, 0); STG(B, Bs, bn, 0, 1, 0);
  if (NT > 1) { STG(A, As, bm, 1, 0, 1); STG(B, Bs, bn, 1, 1, 1); }
  asm volatile("s_waitcnt vmcnt(4)" ::: "memory");
  __builtin_amdgcn_s_barrier();

  f32x4 acc[8][4] = {};
  bfrag a_[4][2], b_[2][2];

#define RD_A(bb, ih)                                                             \
  do {                                                                           \
    const char* ab = (const char*)As[bb] + aoff + (ih) * 8192;                   \
    _Pragma("unroll") for (int i = 0; i < 4; ++i)                                \
      _Pragma("unroll") for (int ks = 0; ks < 2; ++ks)                           \
        a_[i][ks] = *(const bfrag*)(ab + i * 2048 + ch[ks]);                     \
  } while (0)
#define RD_B(bb, jh)                                                             \
  do {                                                                           \
    const char* bb_ = (const char*)Bs[bb] + boff_ + (jh) * 4096;                 \
    _Pragma("unroll") for (int j = 0; j < 2; ++j)                                \
      _Pragma("unroll") for (int ks = 0; ks < 2; ++ks)                           \
        b_[j][ks] = *(const bfrag*)(bb_ + j * 2048 + ch[ks]);                    \
  } while (0)
#define MFMA16(ih, jh)                                                           \
  do {                                                                           \
    __builtin_amdgcn_s_setprio(1);                                               \
    _Pragma("unroll") for (int i = 0; i < 4; ++i)                                \
      _Pragma("unroll") for (int j = 0; j < 2; ++j)                              \
        _Pragma("unroll") for (int ks = 0; ks < 2; ++ks)                         \
          acc[(ih) * 4 + i][(jh) * 2 + j] = __builtin_amdgcn_mfma_f32_16x16x32_bf16( \
              a_[i][ks], b_[j][ks], acc[(ih) * 4 + i][(jh) * 2 + j], 0, 0, 0);   \
    __builtin_amdgcn_s_setprio(0);                                               \
  } while (0)

  for (int kt = 0; kt < NT; ++kt) {
    const int b = kt & 1;
    // ---- phase 0: quad (A0,B0); stage A1(kt+1) -> buf b^1 ----
    RD_A(b, 0); RD_B(b, 0);
    if (kt + 1 < NT) STG(A, As, bm, b ^ 1, 1, kt + 1);
    __builtin_amdgcn_s_barrier();
    asm volatile("s_waitcnt lgkmcnt(0)" ::: "memory");
    MFMA16(0, 0);
    __builtin_amdgcn_s_barrier();
    // ---- phase 1: quad (A0,B1); stage B0(kt+1) -> buf b^1 ----
    RD_B(b, 1);
    if (kt + 1 < NT) STG(B, Bs, bn, b ^ 1, 0, kt + 1);
    __builtin_amdgcn_s_barrier();
    asm volatile("s_waitcnt lgkmcnt(0)" ::: "memory");
    MFMA16(0, 1);
    __builtin_amdgcn_s_barrier();
    // ---- phase 2: quad (A1,B1); stage A0(kt+2) -> buf b ----
    RD_A(b, 1);
    if (kt + 2 < NT) STG(A, As, bm, b, 0, kt + 2);
    __builtin_amdgcn_s_barrier();
    asm volatile("s_waitcnt lgkmcnt(0)" ::: "memory");
    MFMA16(1, 1);
    __builtin_amdgcn_s_barrier();
    // ---- phase 3: quad (A1,B0); stage B1(kt+2) -> buf b ----
    RD_B(b, 0);
    if (kt + 2 < NT) STG(B, Bs, bn, b, 1, kt + 2);
    __builtin_amdgcn_s_barrier();
    asm volatile("s_waitcnt lgkmcnt(0)" ::: "memory");
    MFMA16(1, 0);
    asm volatile("s_waitcnt vmcnt(4)" ::: "memory");  // kt+1's half-tiles all landed
    __builtin_amdgcn_s_barrier();
  }
#undef STG
#undef RD_A
#undef RD_B
#undef MFMA16
  // ---- epilogue ----
  const int rb = bm + wm * 128 + lg * 4, cb = bn + wn * 64 + lr;
#pragma unroll
  for (int i = 0; i < 8; ++i)
#pragma unroll
    for (int j = 0; j < 4; ++j)
#pragma unroll
      for (int r = 0; r < 4; ++r) {
        size_t idx = (size_t)(rb + i * 16 + r) * N + (cb + j * 16);
        if (BF16OUT) ((short*)Cv)[idx] = f2bf(acc[i][j][r]);
        else         ((float*)Cv)[idx] = acc[i][j][r];
      }
}

// ---------- RoPE in-place (q heads 0..31, k heads 32..39) ----------
__global__ __launch_bounds__(256) void rope_k(short* __restrict__ qkv,
                                              const float* __restrict__ fcos,
                                              const float* __restrict__ fsin) {
  const int t = blockIdx.x;
  const int s = t & 2047;
  unsigned* row = (unsigned*)(qkv + (size_t)t * 6144);
  for (int p = threadIdx.x; p < 2560; p += 256) {
    const int h = p >> 6, i = p & 63;
    const int w = h * 64 + i;
    unsigned u = row[w];
    float a  = bf2f((short)(u & 0xffff));
    float b  = bf2f((short)(u >> 16));
    float c  = fcos[s * 64 + i], sn = fsin[s * 64 + i];
    float na = a * c - b * sn;
    float nb = a * sn + b * c;
    row[w] = ((unsigned)(unsigned short)f2bf(na)) |
             (((unsigned)(unsigned short)f2bf(nb)) << 16);
  }
}

// ---------- V transpose: qkv V-part [t][d] -> vt[b][kvh][d][s] ----------
__global__ __launch_bounds__(256) void vtrans(const short* __restrict__ qkv,
                                              short* __restrict__ vt) {
  const int sb = blockIdx.x, kvh = blockIdx.y, b = blockIdx.z;
  __shared__ short T[64][136];
  const int tid = threadIdx.x;
#pragma unroll
  for (int it = 0; it < 4; ++it) {
    int c = it * 256 + tid;
    int r = c >> 4, dc = c & 15;
    s16x8 v = *(const s16x8*)(qkv + (size_t)(b * 2048 + sb * 64 + r) * 6144
                              + 5120 + kvh * 128 + dc * 8);
    *(s16x8*)&T[r][dc * 8] = v;
  }
  __syncthreads();
#pragma unroll
  for (int it = 0; it < 4; ++it) {
    int c = it * 256 + tid;
    int d = c >> 3, sc = c & 7;
    s16x8 v;
#pragma unroll
    for (int j = 0; j < 8; ++j) v[j] = T[sc * 8 + j][d];
    *(s16x8*)(vt + (size_t)((b * 8 + kvh) * 128 + d) * 2048 + sb * 64 + sc * 8) = v;
  }
}

// ---------- Flash attention, m214 structure (unchanged) ----------
__global__ __launch_bounds__(512, 2) void fattn2(const short* __restrict__ qkv,
                                                 const short* __restrict__ vt,
                                                 short* __restrict__ ao) {
  const int qb = blockIdx.x, h = blockIdx.y, b = blockIdx.z;
  const int kvh = h >> 2;
  const int tid = threadIdx.x;
  const int lane = tid & 63, wid = tid >> 6;
  const int l31 = lane & 31, hi = lane >> 5;
  __shared__ __align__(16) short Ks[2][64 * 128];
  __shared__ __align__(16) short Vs[2][128 * 64];

  const int q0w   = qb * 256 + wid * 32;
  const int qg    = q0w + l31;
  const int tmaxw = q0w >> 6;
  const int NT    = 4 * qb + 4;

  bfrag qf[8];
  {
    const short* qp = qkv + (size_t)(b * 2048 + qg) * 6144 + h * 128 + hi * 8;
#pragma unroll
    for (int kk = 0; kk < 8; ++kk) qf[kk] = *(const bfrag*)(qp + kk * 16);
  }

  const int kr0 = tid >> 4, kcc = tid & 15;
  const int vd0 = tid >> 3, vkc = tid & 7;
  const int kro[2] = { kr0, kr0 + 32 };
  const int vdo[2] = { vd0, vd0 + 64 };
  int kldst[2], vldst[2];
#pragma unroll
  for (int i = 0; i < 2; ++i) {
    kldst[i] = (kro[i] * 256 + kcc * 16) ^ ((kro[i] & 7) << 4);
    vldst[i] = (vdo[i] * 128 + vkc * 16) ^ ((vdo[i] & 7) << 4);
  }
  const short* base_k = qkv + (size_t)(b * 2048) * 6144 + 4096 + kvh * 128;
  const short* base_v = vt + (size_t)((b * 8 + kvh) * 128) * 2048;

  {
    s16x8 kr_[2], vr_[2];
#pragma unroll
    for (int i = 0; i < 2; ++i) {
      kr_[i] = *(const s16x8*)(base_k + (size_t)kro[i] * 6144 + kcc * 8);
      vr_[i] = *(const s16x8*)(base_v + (size_t)vdo[i] * 2048 + vkc * 8);
    }
#pragma unroll
    for (int i = 0; i < 2; ++i) {
      *(s16x8*)((char*)Ks[0] + kldst[i]) = kr_[i];
      *(s16x8*)((char*)Vs[0] + vldst[i]) = vr_[i];
    }
  }
  __syncthreads();

  f32x16 o[4] = {};
  float m = -3.0e38f, l = 0.f;
  const float c0 = 0.08838834764831845f * 1.4426950408889634f;
  const int  sw = (l31 & 7) << 4;

  for (int t = 0; t < NT; ++t) {
    const int cur = t & 1;
    s16x8 kr_[2], vr_[2];
    const bool pf = (t + 1 < NT);
    if (pf) {
#pragma unroll
      for (int i = 0; i < 2; ++i) {
        kr_[i] = *(const s16x8*)(base_k + (size_t)((t + 1) * 64 + kro[i]) * 6144 + kcc * 8);
        vr_[i] = *(const s16x8*)(base_v + (size_t)vdo[i] * 2048 + (t + 1) * 64 + vkc * 8);
      }
    }
    if (t <= tmaxw) {
      f32x16 st[2];
      __builtin_amdgcn_s_setprio(1);
#pragma unroll
      for (int kt = 0; kt < 2; ++kt) {
        f32x16 acc = {};
        const char* kb = (const char*)Ks[cur] + kt * 8192 + l31 * 256;
#pragma unroll
        for (int kk = 0; kk < 8; ++kk) {
          bfrag kf = *(const bfrag*)(kb + ((kk * 32 + hi * 16) ^ sw));
          acc = __builtin_amdgcn_mfma_f32_32x32x16_bf16(kf, qf[kk], acc, 0, 0, 0);
        }
        st[kt] = acc;
      }
      __builtin_amdgcn_s_setprio(0);
      if (t == tmaxw) {
        const int kb0 = t * 64 + 4 * hi;
#pragma unroll
        for (int kt = 0; kt < 2; ++kt)
#pragma unroll
          for (int r = 0; r < 16; ++r) {
            int k = kb0 + kt * 32 + (r & 3) + 8 * (r >> 2);
            if (k > qg) st[kt][r] = -3.0e38f;
          }
      }
      float mt = -3.0e38f;
#pragma unroll
      for (int kt = 0; kt < 2; ++kt)
#pragma unroll
        for (int r = 0; r < 16; ++r) mt = fmaxf(mt, st[kt][r]);
      mt = fmaxf(mt, __shfl_xor(mt, 32, 64));
      if (!__all((mt - m) * c0 <= 8.0f)) {
        float nm = fmaxf(m, mt);
        float fe = exp2f((m - nm) * c0);
        m = nm;
        l *= fe;
#pragma unroll
        for (int dt = 0; dt < 4; ++dt)
#pragma unroll
          for (int r = 0; r < 16; ++r) o[dt][r] *= fe;
      }
      const float mc = m * c0;
      float ps = 0.f;
#pragma unroll
      for (int kt = 0; kt < 2; ++kt)
#pragma unroll
        for (int r = 0; r < 16; ++r) {
          float p = exp2f(st[kt][r] * c0 - mc);
          st[kt][r] = p;
          ps += p;
        }
      ps += __shfl_xor(ps, 32, 64);
      l += ps;
      bfrag pfr[4];
#pragma unroll
      for (int kt = 0; kt < 2; ++kt) {
        u32x2 a0 = __builtin_amdgcn_permlane32_swap(cvtpk(st[kt][0],  st[kt][1]),
                                                    cvtpk(st[kt][4],  st[kt][5]),  0, 0);
        u32x2 a1 = __builtin_amdgcn_permlane32_swap(cvtpk(st[kt][2],  st[kt][3]),
                                                    cvtpk(st[kt][6],  st[kt][7]),  0, 0);
        u32x2 b0 = __builtin_amdgcn_permlane32_swap(cvtpk(st[kt][8],  st[kt][9]),
                                                    cvtpk(st[kt][12], st[kt][13]), 0, 0);
        u32x2 b1 = __builtin_amdgcn_permlane32_swap(cvtpk(st[kt][10], st[kt][11]),
                                                    cvtpk(st[kt][14], st[kt][15]), 0, 0);
        u32x4 w0 = { a0.x, a1.x, a0.y, a1.y };
        u32x4 w1 = { b0.x, b1.x, b0.y, b1.y };
        pfr[kt * 2]     = __builtin_bit_cast(bfrag, w0);
        pfr[kt * 2 + 1] = __builtin_bit_cast(bfrag, w1);
      }
      __builtin_amdgcn_s_setprio(1);
#pragma unroll
      for (int ks = 0; ks < 4; ++ks) {
        const char* vb = (const char*)Vs[cur] + l31 * 128 + ((ks * 32 + hi * 16) ^ sw);
#pragma unroll
        for (int dt = 0; dt < 4; ++dt) {
          bfrag vf = *(const bfrag*)(vb + dt * 4096);
          o[dt] = __builtin_amdgcn_mfma_f32_32x32x16_bf16(vf, pfr[ks], o[dt], 0, 0, 0);
        }
      }
      __builtin_amdgcn_s_setprio(0);
    }
    __syncthreads();
    if (pf) {
#pragma unroll
      for (int i = 0; i < 2; ++i) {
        *(s16x8*)((char*)Ks[cur ^ 1] + kldst[i]) = kr_[i];
        *(s16x8*)((char*)Vs[cur ^ 1] + vldst[i]) = vr_[i];
      }
    }
    __syncthreads();
  }
  const float linv = 1.f / l;
  short* aop = ao + (size_t)(b * 2048 + qg) * 4096 + h * 128 + 4 * hi;
#pragma unroll
  for (int dt = 0; dt < 4; ++dt)
#pragma unroll
    for (int r = 0; r < 16; ++r) {
      int d = dt * 32 + (r & 3) + 8 * (r >> 2);
      aop[d] = f2bf(o[dt][r] * linv);
    }
}

// ---------- launch ----------
extern "C" void kernel_launch(void* const* d_in, const int* in_sizes, int n_in,
                              void* d_out, int out_size, void* d_ws, size_t ws_size,
                              hipStream_t stream) {
  const float* x  = (const float*)d_in[0];
  const float* wq = (const float*)d_in[1];
  const float* wk = (const float*)d_in[2];
  const float* wv = (const float*)d_in[3];
  const float* wo = (const float*)d_in[4];
  const float* fc = (const float*)d_in[7];
  const float* fs = (const float*)d_in[8];

  char* ws = (char*)d_ws;
  short* xb    = (short*)(ws);                    // [4096][4096] bf16; reused as ao
  short* ao    = xb;
  short* wqkvb = (short*)(ws + 33554432ull);      // [6144][4096] bf16; reused as wob
  short* wob   = wqkvb;
  short* qkv   = (short*)(ws + 83886080ull);      // [4096][6144] bf16
  short* vt    = (short*)(ws + 134217728ull);     // [2][8][128][2048] bf16

  cvt_f32_bf16<<<16384, 256, 0, stream>>>(x,  xb,                 4194304);
  cvt_f32_bf16<<<16384, 256, 0, stream>>>(wq, wqkvb,              4194304);
  cvt_f32_bf16<<< 4096, 256, 0, stream>>>(wk, wqkvb + 16777216,   1048576);
  cvt_f32_bf16<<< 4096, 256, 0, stream>>>(wv, wqkvb + 20971520,   1048576);
  gemm256<true ><<<384, 512, 0, stream>>>(xb, wqkvb, qkv, 4096, 6144, 4096, 24);
  rope_k<<<4096, 256, 0, stream>>>(qkv, fc, fs);
  vtrans<<<dim3(32, 8, 2), 256, 0, stream>>>(qkv, vt);
  fattn2<<<dim3(8, 32, 2), 512, 0, stream>>>(qkv, vt, ao);
  cvt_f32_bf16<<<16384, 256, 0, stream>>>(wo, wob,                4194304);
  gemm256<false><<<256, 512, 0, stream>>>(ao, wob, (float*)d_out, 4096, 4096, 4096, 16);
}

// Round 5
// 586.646 us; speedup vs baseline: 1.4600x; 1.0381x over previous
//
#include <hip/hip_runtime.h>
#include <hip/hip_bf16.h>
#include <math.h>

// ---------- types ----------
typedef __attribute__((ext_vector_type(8)))  __bf16 bfrag;   // MFMA A/B operand (8 bf16)
typedef __attribute__((ext_vector_type(4)))  float  f32x4;
typedef __attribute__((ext_vector_type(16))) float  f32x16;  // 32x32 MFMA C/D
typedef __attribute__((ext_vector_type(8)))  short  s16x8;
typedef __attribute__((ext_vector_type(4)))  short  s16x4;
typedef __attribute__((ext_vector_type(2)))  unsigned u32x2;
typedef __attribute__((ext_vector_type(4)))  unsigned u32x4;

__device__ __forceinline__ short f2bf(float f) {
  return (short)__builtin_bit_cast(unsigned short, (__bf16)f);
}
__device__ __forceinline__ float bf2f(short s) {
  return (float)__builtin_bit_cast(__bf16, (unsigned short)s);
}
__device__ __forceinline__ unsigned cvtpk(float lo, float hi_) {
  unsigned r;
  asm("v_cvt_pk_bf16_f32 %0, %1, %2" : "=v"(r) : "v"(lo), "v"(hi_));
  return r;
}
__device__ __forceinline__ void gll16(const void* g, void* l) {
  __builtin_amdgcn_global_load_lds((const __attribute__((address_space(1))) void*)g,
                                   (__attribute__((address_space(3))) void*)l, 16, 0, 0);
}

// ---------- f32 -> bf16 convert ----------
__global__ __launch_bounds__(256) void cvt_f32_bf16(const float* __restrict__ in,
                                                    short* __restrict__ out, int n4) {
  int i = blockIdx.x * 256 + threadIdx.x;
  if (i >= n4) return;
  f32x4 v = ((const f32x4*)in)[i];
  s16x4 o;
  o.x = f2bf(v.x); o.y = f2bf(v.y); o.z = f2bf(v.z); o.w = f2bf(v.w);
  ((s16x4*)out)[i] = o;
}

// ---------- GEMM 256x256, BK=64, 2-barriers-per-K-tile free-run schedule ----------
// C[M][N] = A[M][K] @ B[N][K]^T, bf16 in, f32 acc. 8 waves (2M x 4N).
// Per K-tile: 4 quads of 16 MFMA = 64 MFMA, ONE mid barrier + ONE boundary barrier
// (32 MFMA/barrier, AITER ratio). Waves free-run within each half -> LDS drain of
// one wave overlaps MFMA of another (m114). Counted vmcnt(4) at boundary only.
// Region analysis (half-tile = 128 rows): all 4 halves first-read at p0; A-halves
// last-read p2, B-halves last-read p1 (B frags kept in regs). Stage slots:
//   p0/p1 -> A-halves(kt+1) into buf^1  (WAR: A(kt-1) reads done at boundary(kt-1))
//   p2/p3 -> B-halves(kt+2) into buf    (WAR: B(kt) last read p1 < mid-barrier)
// Boundary vmcnt(4): 12 outstanding, waits oldest 8 = all of kt+1; B(kt+2) in flight.
template<bool BF16OUT>
__global__ __launch_bounds__(512) void gemm256(const short* __restrict__ A,
                                               const short* __restrict__ B,
                                               void* __restrict__ Cv,
                                               int M, int N, int K, int NBX) {
  __shared__ __align__(16) short As[2][256 * 64];   // 2 x 32 KB
  __shared__ __align__(16) short Bs[2][256 * 64];   // 2 x 32 KB (total 128 KB)
  const int tid = threadIdx.x, lane = tid & 63, wid = tid >> 6;
  const int lr = lane & 15, lg = lane >> 4;
  const int wm = wid >> 2, wn = wid & 3;
  // bijective XCD-aware block swizzle (m204)
  const int nwg = gridDim.x, orig = blockIdx.x;
  const int qq = nwg >> 3, rr = nwg & 7, xc = orig & 7, o8 = orig >> 3;
  const int wg = (xc < rr ? xc * (qq + 1) : rr * (qq + 1) + (xc - rr) * qq) + o8;
  const int bm = (wg / NBX) << 8, bn = (wg % NBX) << 8;
  const int NT = K >> 6;
  // staging mapping: half-tile = 128 rows x 64 cols = 4 gll16 waves-rounds (2 per STG)
  const int r0 = tid >> 3;                 // row within 64-row stripe
  const int c0 = tid & 7;
  const int csrc = c0 ^ (r0 & 7);          // inverse-swizzled 16B source chunk

#define STG(OP, OPs, boff, bb, hh, kt_)                                          \
  do {                                                                           \
    _Pragma("unroll")                                                            \
    for (int s = 0; s < 2; ++s)                                                  \
      gll16(OP + (size_t)(boff + (hh) * 128 + s * 64 + r0) * K + (kt_) * 64 + csrc * 8, \
            (char*)OPs[bb] + ((hh) * 128 + s * 64 + wid * 8) * 128);             \
  } while (0)

  // ds_read swizzled chunk offsets: element chunk (ks*4+lg) ^ (lr&7), x16 bytes
  int ch[2];
#pragma unroll
  for (int ks = 0; ks < 2; ++ks) ch[ks] = (((ks << 2) | lg) ^ (lr & 7)) << 4;
  const int aoff = (wm * 128 + lr) * 128;
  const int boff_ = (wn * 64 + lr) * 128;

#define RD_A(dst, bb, ih)                                                        \
  do {                                                                           \
    const char* ab = (const char*)As[bb] + aoff + (ih) * 8192;                   \
    _Pragma("unroll") for (int i = 0; i < 4; ++i)                                \
      _Pragma("unroll") for (int ks = 0; ks < 2; ++ks)                           \
        dst[i][ks] = *(const bfrag*)(ab + i * 2048 + ch[ks]);                    \
  } while (0)
#define RD_B(dst, bb, jh)                                                        \
  do {                                                                           \
    const char* bp = (const char*)Bs[bb] + boff_ + (jh) * 4096;                  \
    _Pragma("unroll") for (int j = 0; j < 2; ++j)                                \
      _Pragma("unroll") for (int ks = 0; ks < 2; ++ks)                           \
        dst[j][ks] = *(const bfrag*)(bp + j * 2048 + ch[ks]);                    \
  } while (0)
#define MFMA16(af, bf, ih, jh)                                                   \
  do {                                                                           \
    __builtin_amdgcn_s_setprio(1);                                               \
    _Pragma("unroll") for (int i = 0; i < 4; ++i)                                \
      _Pragma("unroll") for (int j = 0; j < 2; ++j)                              \
        _Pragma("unroll") for (int ks = 0; ks < 2; ++ks)                         \
          acc[(ih) * 4 + i][(jh) * 2 + j] = __builtin_amdgcn_mfma_f32_16x16x32_bf16( \
              af[i][ks], bf[j][ks], acc[(ih) * 4 + i][(jh) * 2 + j], 0, 0, 0);   \
    __builtin_amdgcn_s_setprio(0);                                               \
  } while (0)

  // ---- prologue: tile 0 fully; B-halves of tile 1 (the "p2/p3(kt-1)" slots) ----
  STG(A, As, bm, 0, 0, 0); STG(A, As, bm, 0, 1, 0);
  STG(B, Bs, bn, 0, 0, 0); STG(B, Bs, bn, 0, 1, 0);
  if (NT > 1) {
    STG(B, Bs, bn, 1, 0, 1); STG(B, Bs, bn, 1, 1, 1);
    asm volatile("s_waitcnt vmcnt(4)" ::: "memory");
  } else {
    asm volatile("s_waitcnt vmcnt(0)" ::: "memory");
  }
  __builtin_amdgcn_s_barrier();
  __builtin_amdgcn_sched_barrier(0);

  f32x4 acc[8][4] = {};
  bfrag a_[4][2], b_lo[2][2], b_hi[2][2];

  for (int kt = 0; kt < NT; ++kt) {
    const int b = kt & 1;
    // ---- p0: quad (0,0); stage A-half0(kt+1) ----
    RD_A(a_, b, 0);
    RD_B(b_lo, b, 0);
    if (kt + 1 < NT) STG(A, As, bm, b ^ 1, 0, kt + 1);
    MFMA16(a_, b_lo, 0, 0);
    // ---- p1: quad (0,1); stage A-half1(kt+1) ----
    RD_B(b_hi, b, 1);
    if (kt + 1 < NT) STG(A, As, bm, b ^ 1, 1, kt + 1);
    MFMA16(a_, b_hi, 0, 1);
    __builtin_amdgcn_s_barrier();            // mid: B(kt) reads done before p2/p3 B-stages
    __builtin_amdgcn_sched_barrier(0);
    // ---- p2: quad (1,1); stage B-half0(kt+2) ----
    RD_A(a_, b, 1);
    if (kt + 2 < NT) STG(B, Bs, bn, b, 0, kt + 2);
    MFMA16(a_, b_hi, 1, 1);
    // ---- p3: quad (1,0); stage B-half1(kt+2) ----
    if (kt + 2 < NT) STG(B, Bs, bn, b, 1, kt + 2);
    MFMA16(a_, b_lo, 1, 0);
    // ---- boundary: all of kt+1 landed; B(kt+2) stays in flight ----
    if (kt + 1 < NT) {
      if (kt + 2 < NT) asm volatile("s_waitcnt vmcnt(4)" ::: "memory");
      else             asm volatile("s_waitcnt vmcnt(0)" ::: "memory");
      __builtin_amdgcn_s_barrier();
      __builtin_amdgcn_sched_barrier(0);
    }
  }
#undef STG
#undef RD_A
#undef RD_B
#undef MFMA16
  // ---- epilogue ----
  const int rb = bm + wm * 128 + lg * 4, cb = bn + wn * 64 + lr;
#pragma unroll
  for (int i = 0; i < 8; ++i)
#pragma unroll
    for (int j = 0; j < 4; ++j)
#pragma unroll
      for (int r = 0; r < 4; ++r) {
        size_t idx = (size_t)(rb + i * 16 + r) * N + (cb + j * 16);
        if (BF16OUT) ((short*)Cv)[idx] = f2bf(acc[i][j][r]);
        else         ((float*)Cv)[idx] = acc[i][j][r];
      }
}

// ---------- RoPE in-place (q heads 0..31, k heads 32..39) ----------
__global__ __launch_bounds__(256) void rope_k(short* __restrict__ qkv,
                                              const float* __restrict__ fcos,
                                              const float* __restrict__ fsin) {
  const int t = blockIdx.x;
  const int s = t & 2047;
  unsigned* row = (unsigned*)(qkv + (size_t)t * 6144);
  for (int p = threadIdx.x; p < 2560; p += 256) {
    const int h = p >> 6, i = p & 63;
    const int w = h * 64 + i;
    unsigned u = row[w];
    float a  = bf2f((short)(u & 0xffff));
    float b  = bf2f((short)(u >> 16));
    float c  = fcos[s * 64 + i], sn = fsin[s * 64 + i];
    float na = a * c - b * sn;
    float nb = a * sn + b * c;
    row[w] = ((unsigned)(unsigned short)f2bf(na)) |
             (((unsigned)(unsigned short)f2bf(nb)) << 16);
  }
}

// ---------- V transpose: qkv V-part [t][d] -> vt[b][kvh][d][s] ----------
__global__ __launch_bounds__(256) void vtrans(const short* __restrict__ qkv,
                                              short* __restrict__ vt) {
  const int sb = blockIdx.x, kvh = blockIdx.y, b = blockIdx.z;
  __shared__ short T[64][136];
  const int tid = threadIdx.x;
#pragma unroll
  for (int it = 0; it < 4; ++it) {
    int c = it * 256 + tid;
    int r = c >> 4, dc = c & 15;
    s16x8 v = *(const s16x8*)(qkv + (size_t)(b * 2048 + sb * 64 + r) * 6144
                              + 5120 + kvh * 128 + dc * 8);
    *(s16x8*)&T[r][dc * 8] = v;
  }
  __syncthreads();
#pragma unroll
  for (int it = 0; it < 4; ++it) {
    int c = it * 256 + tid;
    int d = c >> 3, sc = c & 7;
    s16x8 v;
#pragma unroll
    for (int j = 0; j < 8; ++j) v[j] = T[sc * 8 + j][d];
    *(s16x8*)(vt + (size_t)((b * 8 + kvh) * 128 + d) * 2048 + sb * 64 + sc * 8) = v;
  }
}

// ---------- Flash attention, m214 structure (unchanged) ----------
__global__ __launch_bounds__(512, 2) void fattn2(const short* __restrict__ qkv,
                                                 const short* __restrict__ vt,
                                                 short* __restrict__ ao) {
  const int qb = blockIdx.x, h = blockIdx.y, b = blockIdx.z;
  const int kvh = h >> 2;
  const int tid = threadIdx.x;
  const int lane = tid & 63, wid = tid >> 6;
  const int l31 = lane & 31, hi = lane >> 5;
  __shared__ __align__(16) short Ks[2][64 * 128];
  __shared__ __align__(16) short Vs[2][128 * 64];

  const int q0w   = qb * 256 + wid * 32;
  const int qg    = q0w + l31;
  const int tmaxw = q0w >> 6;
  const int NT    = 4 * qb + 4;

  bfrag qf[8];
  {
    const short* qp = qkv + (size_t)(b * 2048 + qg) * 6144 + h * 128 + hi * 8;
#pragma unroll
    for (int kk = 0; kk < 8; ++kk) qf[kk] = *(const bfrag*)(qp + kk * 16);
  }

  const int kr0 = tid >> 4, kcc = tid & 15;
  const int vd0 = tid >> 3, vkc = tid & 7;
  const int kro[2] = { kr0, kr0 + 32 };
  const int vdo[2] = { vd0, vd0 + 64 };
  int kldst[2], vldst[2];
#pragma unroll
  for (int i = 0; i < 2; ++i) {
    kldst[i] = (kro[i] * 256 + kcc * 16) ^ ((kro[i] & 7) << 4);
    vldst[i] = (vdo[i] * 128 + vkc * 16) ^ ((vdo[i] & 7) << 4);
  }
  const short* base_k = qkv + (size_t)(b * 2048) * 6144 + 4096 + kvh * 128;
  const short* base_v = vt + (size_t)((b * 8 + kvh) * 128) * 2048;

  {
    s16x8 kr_[2], vr_[2];
#pragma unroll
    for (int i = 0; i < 2; ++i) {
      kr_[i] = *(const s16x8*)(base_k + (size_t)kro[i] * 6144 + kcc * 8);
      vr_[i] = *(const s16x8*)(base_v + (size_t)vdo[i] * 2048 + vkc * 8);
    }
#pragma unroll
    for (int i = 0; i < 2; ++i) {
      *(s16x8*)((char*)Ks[0] + kldst[i]) = kr_[i];
      *(s16x8*)((char*)Vs[0] + vldst[i]) = vr_[i];
    }
  }
  __syncthreads();

  f32x16 o[4] = {};
  float m = -3.0e38f, l = 0.f;
  const float c0 = 0.08838834764831845f * 1.4426950408889634f;
  const int  sw = (l31 & 7) << 4;

  for (int t = 0; t < NT; ++t) {
    const int cur = t & 1;
    s16x8 kr_[2], vr_[2];
    const bool pf = (t + 1 < NT);
    if (pf) {
#pragma unroll
      for (int i = 0; i < 2; ++i) {
        kr_[i] = *(const s16x8*)(base_k + (size_t)((t + 1) * 64 + kro[i]) * 6144 + kcc * 8);
        vr_[i] = *(const s16x8*)(base_v + (size_t)vdo[i] * 2048 + (t + 1) * 64 + vkc * 8);
      }
    }
    if (t <= tmaxw) {
      f32x16 st[2];
      __builtin_amdgcn_s_setprio(1);
#pragma unroll
      for (int kt = 0; kt < 2; ++kt) {
        f32x16 acc = {};
        const char* kb = (const char*)Ks[cur] + kt * 8192 + l31 * 256;
#pragma unroll
        for (int kk = 0; kk < 8; ++kk) {
          bfrag kf = *(const bfrag*)(kb + ((kk * 32 + hi * 16) ^ sw));
          acc = __builtin_amdgcn_mfma_f32_32x32x16_bf16(kf, qf[kk], acc, 0, 0, 0);
        }
        st[kt] = acc;
      }
      __builtin_amdgcn_s_setprio(0);
      if (t == tmaxw) {
        const int kb0 = t * 64 + 4 * hi;
#pragma unroll
        for (int kt = 0; kt < 2; ++kt)
#pragma unroll
          for (int r = 0; r < 16; ++r) {
            int k = kb0 + kt * 32 + (r & 3) + 8 * (r >> 2);
            if (k > qg) st[kt][r] = -3.0e38f;
          }
      }
      float mt = -3.0e38f;
#pragma unroll
      for (int kt = 0; kt < 2; ++kt)
#pragma unroll
        for (int r = 0; r < 16; ++r) mt = fmaxf(mt, st[kt][r]);
      mt = fmaxf(mt, __shfl_xor(mt, 32, 64));
      if (!__all((mt - m) * c0 <= 8.0f)) {
        float nm = fmaxf(m, mt);
        float fe = exp2f((m - nm) * c0);
        m = nm;
        l *= fe;
#pragma unroll
        for (int dt = 0; dt < 4; ++dt)
#pragma unroll
          for (int r = 0; r < 16; ++r) o[dt][r] *= fe;
      }
      const float mc = m * c0;
      float ps = 0.f;
#pragma unroll
      for (int kt = 0; kt < 2; ++kt)
#pragma unroll
        for (int r = 0; r < 16; ++r) {
          float p = exp2f(st[kt][r] * c0 - mc);
          st[kt][r] = p;
          ps += p;
        }
      ps += __shfl_xor(ps, 32, 64);
      l += ps;
      bfrag pfr[4];
#pragma unroll
      for (int kt = 0; kt < 2; ++kt) {
        u32x2 a0 = __builtin_amdgcn_permlane32_swap(cvtpk(st[kt][0],  st[kt][1]),
                                                    cvtpk(st[kt][4],  st[kt][5]),  0, 0);
        u32x2 a1 = __builtin_amdgcn_permlane32_swap(cvtpk(st[kt][2],  st[kt][3]),
                                                    cvtpk(st[kt][6],  st[kt][7]),  0, 0);
        u32x2 b0 = __builtin_amdgcn_permlane32_swap(cvtpk(st[kt][8],  st[kt][9]),
                                                    cvtpk(st[kt][12], st[kt][13]), 0, 0);
        u32x2 b1 = __builtin_amdgcn_permlane32_swap(cvtpk(st[kt][10], st[kt][11]),
                                                    cvtpk(st[kt][14], st[kt][15]), 0, 0);
        u32x4 w0 = { a0.x, a1.x, a0.y, a1.y };
        u32x4 w1 = { b0.x, b1.x, b0.y, b1.y };
        pfr[kt * 2]     = __builtin_bit_cast(bfrag, w0);
        pfr[kt * 2 + 1] = __builtin_bit_cast(bfrag, w1);
      }
      __builtin_amdgcn_s_setprio(1);
#pragma unroll
      for (int ks = 0; ks < 4; ++ks) {
        const char* vb = (const char*)Vs[cur] + l31 * 128 + ((ks * 32 + hi * 16) ^ sw);
#pragma unroll
        for (int dt = 0; dt < 4; ++dt) {
          bfrag vf = *(const bfrag*)(vb + dt * 4096);
          o[dt] = __builtin_amdgcn_mfma_f32_32x32x16_bf16(vf, pfr[ks], o[dt], 0, 0, 0);
        }
      }
      __builtin_amdgcn_s_setprio(0);
    }
    __syncthreads();
    if (pf) {
#pragma unroll
      for (int i = 0; i < 2; ++i) {
        *(s16x8*)((char*)Ks[cur ^ 1] + kldst[i]) = kr_[i];
        *(s16x8*)((char*)Vs[cur ^ 1] + vldst[i]) = vr_[i];
      }
    }
    __syncthreads();
  }
  const float linv = 1.f / l;
  short* aop = ao + (size_t)(b * 2048 + qg) * 4096 + h * 128 + 4 * hi;
#pragma unroll
  for (int dt = 0; dt < 4; ++dt)
#pragma unroll
    for (int r = 0; r < 16; ++r) {
      int d = dt * 32 + (r & 3) + 8 * (r >> 2);
      aop[d] = f2bf(o[dt][r] * linv);
    }
}

// ---------- launch ----------
extern "C" void kernel_launch(void* const* d_in, const int* in_sizes, int n_in,
                              void* d_out, int out_size, void* d_ws, size_t ws_size,
                              hipStream_t stream) {
  const float* x  = (const float*)d_in[0];
  const float* wq = (const float*)d_in[1];
  const float* wk = (const float*)d_in[2];
  const float* wv = (const float*)d_in[3];
  const float* wo = (const float*)d_in[4];
  const float* fc = (const float*)d_in[7];
  const float* fs = (const float*)d_in[8];

  char* ws = (char*)d_ws;
  short* xb    = (short*)(ws);                    // [4096][4096] bf16; reused as ao
  short* ao    = xb;
  short* wqkvb = (short*)(ws + 33554432ull);      // [6144][4096] bf16; reused as wob
  short* wob   = wqkvb;
  short* qkv   = (short*)(ws + 83886080ull);      // [4096][6144] bf16
  short* vt    = (short*)(ws + 134217728ull);     // [2][8][128][2048] bf16

  cvt_f32_bf16<<<16384, 256, 0, stream>>>(x,  xb,                 4194304);
  cvt_f32_bf16<<<16384, 256, 0, stream>>>(wq, wqkvb,              4194304);
  cvt_f32_bf16<<< 4096, 256, 0, stream>>>(wk, wqkvb + 16777216,   1048576);
  cvt_f32_bf16<<< 4096, 256, 0, stream>>>(wv, wqkvb + 20971520,   1048576);
  gemm256<true ><<<384, 512, 0, stream>>>(xb, wqkvb, qkv, 4096, 6144, 4096, 24);
  rope_k<<<4096, 256, 0, stream>>>(qkv, fc, fs);
  vtrans<<<dim3(32, 8, 2), 256, 0, stream>>>(qkv, vt);
  fattn2<<<dim3(8, 32, 2), 512, 0, stream>>>(qkv, vt, ao);
  cvt_f32_bf16<<<16384, 256, 0, stream>>>(wo, wob,                4194304);
  gemm256<false><<<256, 512, 0, stream>>>(ao, wob, (float*)d_out, 4096, 4096, 4096, 16);
}

// Round 6
// 583.764 us; speedup vs baseline: 1.4672x; 1.0049x over previous
//
#include <hip/hip_runtime.h>
#include <hip/hip_bf16.h>
#include <math.h>

// ---------- types ----------
typedef __attribute__((ext_vector_type(8)))  __bf16 bfrag;   // MFMA A/B operand (8 bf16)
typedef __attribute__((ext_vector_type(4)))  float  f32x4;
typedef __attribute__((ext_vector_type(16))) float  f32x16;  // 32x32 MFMA C/D
typedef __attribute__((ext_vector_type(8)))  short  s16x8;
typedef __attribute__((ext_vector_type(4)))  short  s16x4;
typedef __attribute__((ext_vector_type(2)))  unsigned u32x2;
typedef __attribute__((ext_vector_type(4)))  unsigned u32x4;

__device__ __forceinline__ short f2bf(float f) {
  return (short)__builtin_bit_cast(unsigned short, (__bf16)f);
}
__device__ __forceinline__ float bf2f(short s) {
  return (float)__builtin_bit_cast(__bf16, (unsigned short)s);
}
__device__ __forceinline__ unsigned cvtpk(float lo, float hi_) {
  unsigned r;
  asm("v_cvt_pk_bf16_f32 %0, %1, %2" : "=v"(r) : "v"(lo), "v"(hi_));
  return r;
}
__device__ __forceinline__ void gll16(const void* g, void* l) {
  __builtin_amdgcn_global_load_lds((const __attribute__((address_space(1))) void*)g,
                                   (__attribute__((address_space(3))) void*)l, 16, 0, 0);
}

// ---------- f32 -> bf16 convert ----------
__global__ __launch_bounds__(256) void cvt_f32_bf16(const float* __restrict__ in,
                                                    short* __restrict__ out, int n4) {
  int i = blockIdx.x * 256 + threadIdx.x;
  if (i >= n4) return;
  f32x4 v = ((const f32x4*)in)[i];
  s16x4 o;
  o.x = f2bf(v.x); o.y = f2bf(v.y); o.z = f2bf(v.z); o.w = f2bf(v.w);
  ((s16x4*)out)[i] = o;
}

// ---------- GEMM 128x256 tile, BK=64, 2-phase free-run, ZERO grid tail ----------
// C[M][N] = A[M][K] @ B[N][K]^T, bf16 in, bf16 out. 8 waves (2M x 4N).
// Per-wave 64x64 output; wave cols = wn*32 + jh*128 (jh phase-half) so each
// phase's B region is a contiguous 128-row half of the B tile.
// Per K-tile: p0 {RD_A(8) + RD_Blo(4); STG Bhi(kt+1)->buf^1; 16 MFMA} midbar
//             p1 {RD_Bhi(4); STG A(kt+2)+Blo(kt+2)->buf; 16 MFMA} vmcnt(4) bar
// WAR: every region's last ds_read is consumed by an MFMA before the barrier
// preceding its overwrite. Queue at boundary = 10 gll; vmcnt(4) drains kt+1.
__global__ __launch_bounds__(512) void gemm128n(const short* __restrict__ A,
                                                const short* __restrict__ B,
                                                short* __restrict__ C,
                                                int M, int N, int K, int NBX) {
  __shared__ __align__(16) short As[2][128 * 64];   // 2 x 16 KB
  __shared__ __align__(16) short Bs[2][256 * 64];   // 2 x 32 KB (total 96 KB)
  const int tid = threadIdx.x, lane = tid & 63, wid = tid >> 6;
  const int lr = lane & 15, lg = lane >> 4;
  const int wm = wid >> 2, wn = wid & 3;
  // bijective XCD-aware block swizzle (m204)
  const int nwg = gridDim.x, orig = blockIdx.x;
  const int qq = nwg >> 3, rr = nwg & 7, xc = orig & 7, o8 = orig >> 3;
  const int wg = (xc < rr ? xc * (qq + 1) : rr * (qq + 1) + (xc - rr) * qq) + o8;
  const int bm = (wg / NBX) << 7, bn = (wg % NBX) << 8;
  const int NT = K >> 6;
  // staging: unit = 128 rows x 64 cols = 2 rounds of 512 thr x 16B
  const int r0 = tid >> 3;                 // row within 64-row stripe
  const int c0 = tid & 7;
  const int csrc = c0 ^ (r0 & 7);          // inverse-swizzled 16B source chunk

#define STG(OP, OPs, boff, bb, hh, kt_)                                          \
  do {                                                                           \
    _Pragma("unroll")                                                            \
    for (int s = 0; s < 2; ++s)                                                  \
      gll16(OP + (size_t)(boff + (hh) * 128 + s * 64 + r0) * K + (kt_) * 64 + csrc * 8, \
            (char*)OPs[bb] + ((hh) * 128 + s * 64 + wid * 8) * 128);             \
  } while (0)

  int ch[2];
#pragma unroll
  for (int ks = 0; ks < 2; ++ks) ch[ks] = (((ks << 2) | lg) ^ (lr & 7)) << 4;
  const int aoff  = (wm * 64 + lr) * 128;   // A LDS byte base (row stride 128B)
  const int boff2 = (wn * 32 + lr) * 128;   // B LDS byte base

#define RD_A(dst, bb)                                                            \
  do {                                                                           \
    const char* ab = (const char*)As[bb] + aoff;                                 \
    _Pragma("unroll") for (int i = 0; i < 4; ++i)                                \
      _Pragma("unroll") for (int ks = 0; ks < 2; ++ks)                           \
        dst[i][ks] = *(const bfrag*)(ab + i * 2048 + ch[ks]);                    \
  } while (0)
#define RD_B(dst, bb, jh)                                                        \
  do {                                                                           \
    const char* bp = (const char*)Bs[bb] + boff2 + (jh) * 16384;                 \
    _Pragma("unroll") for (int j = 0; j < 2; ++j)                                \
      _Pragma("unroll") for (int ks = 0; ks < 2; ++ks)                           \
        dst[j][ks] = *(const bfrag*)(bp + j * 2048 + ch[ks]);                    \
  } while (0)
#define MFMA16(af, bf, jh)                                                       \
  do {                                                                           \
    __builtin_amdgcn_s_setprio(1);                                               \
    _Pragma("unroll") for (int i = 0; i < 4; ++i)                                \
      _Pragma("unroll") for (int j = 0; j < 2; ++j)                              \
        _Pragma("unroll") for (int ks = 0; ks < 2; ++ks)                         \
          acc[i][(jh) * 2 + j] = __builtin_amdgcn_mfma_f32_16x16x32_bf16(        \
              af[i][ks], bf[j][ks], acc[i][(jh) * 2 + j], 0, 0, 0);              \
    __builtin_amdgcn_s_setprio(0);                                               \
  } while (0)

  // ---- prologue: A(0), Blo(0), Bhi(0) -> buf0; A(1), Blo(1) -> buf1 ----
  STG(A, As, bm, 0, 0, 0);
  STG(B, Bs, bn, 0, 0, 0);
  STG(B, Bs, bn, 0, 1, 0);
  if (NT > 1) {
    STG(A, As, bm, 1, 0, 1);
    STG(B, Bs, bn, 1, 0, 1);
    asm volatile("s_waitcnt vmcnt(4)" ::: "memory");
  } else {
    asm volatile("s_waitcnt vmcnt(0)" ::: "memory");
  }
  __builtin_amdgcn_s_barrier();
  __builtin_amdgcn_sched_barrier(0);

  f32x4 acc[4][4] = {};
  bfrag a_[4][2], b_lo[2][2], b_hi[2][2];

  for (int kt = 0; kt < NT; ++kt) {
    const int b = kt & 1;
    // ---- p0: quad (A, B_lo); stage B_hi(kt+1) -> buf^1 ----
    RD_A(a_, b);
    RD_B(b_lo, b, 0);
    if (kt + 1 < NT) STG(B, Bs, bn, b ^ 1, 1, kt + 1);
    MFMA16(a_, b_lo, 0);
    __builtin_amdgcn_s_barrier();          // mid: A(kt)/Blo(kt) reads drained by MFMA
    __builtin_amdgcn_sched_barrier(0);
    // ---- p1: quad (A, B_hi); stage A(kt+2), B_lo(kt+2) -> buf ----
    RD_B(b_hi, b, 1);
    if (kt + 2 < NT) {
      STG(A, As, bm, b, 0, kt + 2);
      STG(B, Bs, bn, b, 0, kt + 2);
    }
    MFMA16(a_, b_hi, 1);
    // ---- boundary: kt+1 fully landed; kt+2 stays in flight ----
    if (kt + 1 < NT) {
      if (kt + 2 < NT) asm volatile("s_waitcnt vmcnt(4)" ::: "memory");
      else             asm volatile("s_waitcnt vmcnt(0)" ::: "memory");
      __builtin_amdgcn_s_barrier();
      __builtin_amdgcn_sched_barrier(0);
    }
  }
#undef STG
#undef RD_A
#undef RD_B
#undef MFMA16
  // ---- epilogue ----
  const int rb = bm + wm * 64 + lg * 4, cb = bn + wn * 32 + lr;
#pragma unroll
  for (int i = 0; i < 4; ++i)
#pragma unroll
    for (int jh = 0; jh < 2; ++jh)
#pragma unroll
      for (int j = 0; j < 2; ++j)
#pragma unroll
        for (int r = 0; r < 4; ++r)
          C[(size_t)(rb + i * 16 + r) * N + (cb + jh * 128 + j * 16)] =
              f2bf(acc[i][jh * 2 + j][r]);
}

// ---------- GEMM 256x256, BK=64, 2-barriers-per-K-tile (round-5, for out-proj) ----------
template<bool BF16OUT>
__global__ __launch_bounds__(512) void gemm256(const short* __restrict__ A,
                                               const short* __restrict__ B,
                                               void* __restrict__ Cv,
                                               int M, int N, int K, int NBX) {
  __shared__ __align__(16) short As[2][256 * 64];
  __shared__ __align__(16) short Bs[2][256 * 64];
  const int tid = threadIdx.x, lane = tid & 63, wid = tid >> 6;
  const int lr = lane & 15, lg = lane >> 4;
  const int wm = wid >> 2, wn = wid & 3;
  const int nwg = gridDim.x, orig = blockIdx.x;
  const int qq = nwg >> 3, rr = nwg & 7, xc = orig & 7, o8 = orig >> 3;
  const int wg = (xc < rr ? xc * (qq + 1) : rr * (qq + 1) + (xc - rr) * qq) + o8;
  const int bm = (wg / NBX) << 8, bn = (wg % NBX) << 8;
  const int NT = K >> 6;
  const int r0 = tid >> 3;
  const int c0 = tid & 7;
  const int csrc = c0 ^ (r0 & 7);

#define STG(OP, OPs, boff, bb, hh, kt_)                                          \
  do {                                                                           \
    _Pragma("unroll")                                                            \
    for (int s = 0; s < 2; ++s)                                                  \
      gll16(OP + (size_t)(boff + (hh) * 128 + s * 64 + r0) * K + (kt_) * 64 + csrc * 8, \
            (char*)OPs[bb] + ((hh) * 128 + s * 64 + wid * 8) * 128);             \
  } while (0)

  int ch[2];
#pragma unroll
  for (int ks = 0; ks < 2; ++ks) ch[ks] = (((ks << 2) | lg) ^ (lr & 7)) << 4;
  const int aoff = (wm * 128 + lr) * 128;
  const int boff_ = (wn * 64 + lr) * 128;

#define RD_A(dst, bb, ih)                                                        \
  do {                                                                           \
    const char* ab = (const char*)As[bb] + aoff + (ih) * 8192;                   \
    _Pragma("unroll") for (int i = 0; i < 4; ++i)                                \
      _Pragma("unroll") for (int ks = 0; ks < 2; ++ks)                           \
        dst[i][ks] = *(const bfrag*)(ab + i * 2048 + ch[ks]);                    \
  } while (0)
#define RD_B(dst, bb, jh)                                                        \
  do {                                                                           \
    const char* bp = (const char*)Bs[bb] + boff_ + (jh) * 4096;                  \
    _Pragma("unroll") for (int j = 0; j < 2; ++j)                                \
      _Pragma("unroll") for (int ks = 0; ks < 2; ++ks)                           \
        dst[j][ks] = *(const bfrag*)(bp + j * 2048 + ch[ks]);                    \
  } while (0)
#define MFMA16(af, bf, ih, jh)                                                   \
  do {                                                                           \
    __builtin_amdgcn_s_setprio(1);                                               \
    _Pragma("unroll") for (int i = 0; i < 4; ++i)                                \
      _Pragma("unroll") for (int j = 0; j < 2; ++j)                              \
        _Pragma("unroll") for (int ks = 0; ks < 2; ++ks)                         \
          acc[(ih) * 4 + i][(jh) * 2 + j] = __builtin_amdgcn_mfma_f32_16x16x32_bf16( \
              af[i][ks], bf[j][ks], acc[(ih) * 4 + i][(jh) * 2 + j], 0, 0, 0);   \
    __builtin_amdgcn_s_setprio(0);                                               \
  } while (0)

  STG(A, As, bm, 0, 0, 0); STG(A, As, bm, 0, 1, 0);
  STG(B, Bs, bn, 0, 0, 0); STG(B, Bs, bn, 0, 1, 0);
  if (NT > 1) {
    STG(B, Bs, bn, 1, 0, 1); STG(B, Bs, bn, 1, 1, 1);
    asm volatile("s_waitcnt vmcnt(4)" ::: "memory");
  } else {
    asm volatile("s_waitcnt vmcnt(0)" ::: "memory");
  }
  __builtin_amdgcn_s_barrier();
  __builtin_amdgcn_sched_barrier(0);

  f32x4 acc[8][4] = {};
  bfrag a_[4][2], b_lo[2][2], b_hi[2][2];

  for (int kt = 0; kt < NT; ++kt) {
    const int b = kt & 1;
    RD_A(a_, b, 0);
    RD_B(b_lo, b, 0);
    if (kt + 1 < NT) STG(A, As, bm, b ^ 1, 0, kt + 1);
    MFMA16(a_, b_lo, 0, 0);
    RD_B(b_hi, b, 1);
    if (kt + 1 < NT) STG(A, As, bm, b ^ 1, 1, kt + 1);
    MFMA16(a_, b_hi, 0, 1);
    __builtin_amdgcn_s_barrier();
    __builtin_amdgcn_sched_barrier(0);
    RD_A(a_, b, 1);
    if (kt + 2 < NT) STG(B, Bs, bn, b, 0, kt + 2);
    MFMA16(a_, b_hi, 1, 1);
    if (kt + 2 < NT) STG(B, Bs, bn, b, 1, kt + 2);
    MFMA16(a_, b_lo, 1, 0);
    if (kt + 1 < NT) {
      if (kt + 2 < NT) asm volatile("s_waitcnt vmcnt(4)" ::: "memory");
      else             asm volatile("s_waitcnt vmcnt(0)" ::: "memory");
      __builtin_amdgcn_s_barrier();
      __builtin_amdgcn_sched_barrier(0);
    }
  }
#undef STG
#undef RD_A
#undef RD_B
#undef MFMA16
  const int rb = bm + wm * 128 + lg * 4, cb = bn + wn * 64 + lr;
#pragma unroll
  for (int i = 0; i < 8; ++i)
#pragma unroll
    for (int j = 0; j < 4; ++j)
#pragma unroll
      for (int r = 0; r < 4; ++r) {
        size_t idx = (size_t)(rb + i * 16 + r) * N + (cb + j * 16);
        if (BF16OUT) ((short*)Cv)[idx] = f2bf(acc[i][j][r]);
        else         ((float*)Cv)[idx] = acc[i][j][r];
      }
}

// ---------- RoPE in-place (q heads 0..31, k heads 32..39) ----------
__global__ __launch_bounds__(256) void rope_k(short* __restrict__ qkv,
                                              const float* __restrict__ fcos,
                                              const float* __restrict__ fsin) {
  const int t = blockIdx.x;
  const int s = t & 2047;
  unsigned* row = (unsigned*)(qkv + (size_t)t * 6144);
  for (int p = threadIdx.x; p < 2560; p += 256) {
    const int h = p >> 6, i = p & 63;
    const int w = h * 64 + i;
    unsigned u = row[w];
    float a  = bf2f((short)(u & 0xffff));
    float b  = bf2f((short)(u >> 16));
    float c  = fcos[s * 64 + i], sn = fsin[s * 64 + i];
    float na = a * c - b * sn;
    float nb = a * sn + b * c;
    row[w] = ((unsigned)(unsigned short)f2bf(na)) |
             (((unsigned)(unsigned short)f2bf(nb)) << 16);
  }
}

// ---------- V transpose: qkv V-part [t][d] -> vt[b][kvh][d][s] ----------
__global__ __launch_bounds__(256) void vtrans(const short* __restrict__ qkv,
                                              short* __restrict__ vt) {
  const int sb = blockIdx.x, kvh = blockIdx.y, b = blockIdx.z;
  __shared__ short T[64][136];
  const int tid = threadIdx.x;
#pragma unroll
  for (int it = 0; it < 4; ++it) {
    int c = it * 256 + tid;
    int r = c >> 4, dc = c & 15;
    s16x8 v = *(const s16x8*)(qkv + (size_t)(b * 2048 + sb * 64 + r) * 6144
                              + 5120 + kvh * 128 + dc * 8);
    *(s16x8*)&T[r][dc * 8] = v;
  }
  __syncthreads();
#pragma unroll
  for (int it = 0; it < 4; ++it) {
    int c = it * 256 + tid;
    int d = c >> 3, sc = c & 7;
    s16x8 v;
#pragma unroll
    for (int j = 0; j < 8; ++j) v[j] = T[sc * 8 + j][d];
    *(s16x8*)(vt + (size_t)((b * 8 + kvh) * 128 + d) * 2048 + sb * 64 + sc * 8) = v;
  }
}

// ---------- Flash attention, m214 structure (unchanged) ----------
__global__ __launch_bounds__(512, 2) void fattn2(const short* __restrict__ qkv,
                                                 const short* __restrict__ vt,
                                                 short* __restrict__ ao) {
  const int qb = blockIdx.x, h = blockIdx.y, b = blockIdx.z;
  const int kvh = h >> 2;
  const int tid = threadIdx.x;
  const int lane = tid & 63, wid = tid >> 6;
  const int l31 = lane & 31, hi = lane >> 5;
  __shared__ __align__(16) short Ks[2][64 * 128];
  __shared__ __align__(16) short Vs[2][128 * 64];

  const int q0w   = qb * 256 + wid * 32;
  const int qg    = q0w + l31;
  const int tmaxw = q0w >> 6;
  const int NT    = 4 * qb + 4;

  bfrag qf[8];
  {
    const short* qp = qkv + (size_t)(b * 2048 + qg) * 6144 + h * 128 + hi * 8;
#pragma unroll
    for (int kk = 0; kk < 8; ++kk) qf[kk] = *(const bfrag*)(qp + kk * 16);
  }

  const int kr0 = tid >> 4, kcc = tid & 15;
  const int vd0 = tid >> 3, vkc = tid & 7;
  const int kro[2] = { kr0, kr0 + 32 };
  const int vdo[2] = { vd0, vd0 + 64 };
  int kldst[2], vldst[2];
#pragma unroll
  for (int i = 0; i < 2; ++i) {
    kldst[i] = (kro[i] * 256 + kcc * 16) ^ ((kro[i] & 7) << 4);
    vldst[i] = (vdo[i] * 128 + vkc * 16) ^ ((vdo[i] & 7) << 4);
  }
  const short* base_k = qkv + (size_t)(b * 2048) * 6144 + 4096 + kvh * 128;
  const short* base_v = vt + (size_t)((b * 8 + kvh) * 128) * 2048;

  {
    s16x8 kr_[2], vr_[2];
#pragma unroll
    for (int i = 0; i < 2; ++i) {
      kr_[i] = *(const s16x8*)(base_k + (size_t)kro[i] * 6144 + kcc * 8);
      vr_[i] = *(const s16x8*)(base_v + (size_t)vdo[i] * 2048 + vkc * 8);
    }
#pragma unroll
    for (int i = 0; i < 2; ++i) {
      *(s16x8*)((char*)Ks[0] + kldst[i]) = kr_[i];
      *(s16x8*)((char*)Vs[0] + vldst[i]) = vr_[i];
    }
  }
  __syncthreads();

  f32x16 o[4] = {};
  float m = -3.0e38f, l = 0.f;
  const float c0 = 0.08838834764831845f * 1.4426950408889634f;
  const int  sw = (l31 & 7) << 4;

  for (int t = 0; t < NT; ++t) {
    const int cur = t & 1;
    s16x8 kr_[2], vr_[2];
    const bool pf = (t + 1 < NT);
    if (pf) {
#pragma unroll
      for (int i = 0; i < 2; ++i) {
        kr_[i] = *(const s16x8*)(base_k + (size_t)((t + 1) * 64 + kro[i]) * 6144 + kcc * 8);
        vr_[i] = *(const s16x8*)(base_v + (size_t)vdo[i] * 2048 + (t + 1) * 64 + vkc * 8);
      }
    }
    if (t <= tmaxw) {
      f32x16 st[2];
      __builtin_amdgcn_s_setprio(1);
#pragma unroll
      for (int kt = 0; kt < 2; ++kt) {
        f32x16 acc = {};
        const char* kb = (const char*)Ks[cur] + kt * 8192 + l31 * 256;
#pragma unroll
        for (int kk = 0; kk < 8; ++kk) {
          bfrag kf = *(const bfrag*)(kb + ((kk * 32 + hi * 16) ^ sw));
          acc = __builtin_amdgcn_mfma_f32_32x32x16_bf16(kf, qf[kk], acc, 0, 0, 0);
        }
        st[kt] = acc;
      }
      __builtin_amdgcn_s_setprio(0);
      if (t == tmaxw) {
        const int kb0 = t * 64 + 4 * hi;
#pragma unroll
        for (int kt = 0; kt < 2; ++kt)
#pragma unroll
          for (int r = 0; r < 16; ++r) {
            int k = kb0 + kt * 32 + (r & 3) + 8 * (r >> 2);
            if (k > qg) st[kt][r] = -3.0e38f;
          }
      }
      float mt = -3.0e38f;
#pragma unroll
      for (int kt = 0; kt < 2; ++kt)
#pragma unroll
        for (int r = 0; r < 16; ++r) mt = fmaxf(mt, st[kt][r]);
      mt = fmaxf(mt, __shfl_xor(mt, 32, 64));
      if (!__all((mt - m) * c0 <= 8.0f)) {
        float nm = fmaxf(m, mt);
        float fe = exp2f((m - nm) * c0);
        m = nm;
        l *= fe;
#pragma unroll
        for (int dt = 0; dt < 4; ++dt)
#pragma unroll
          for (int r = 0; r < 16; ++r) o[dt][r] *= fe;
      }
      const float mc = m * c0;
      float ps = 0.f;
#pragma unroll
      for (int kt = 0; kt < 2; ++kt)
#pragma unroll
        for (int r = 0; r < 16; ++r) {
          float p = exp2f(st[kt][r] * c0 - mc);
          st[kt][r] = p;
          ps += p;
        }
      ps += __shfl_xor(ps, 32, 64);
      l += ps;
      bfrag pfr[4];
#pragma unroll
      for (int kt = 0; kt < 2; ++kt) {
        u32x2 a0 = __builtin_amdgcn_permlane32_swap(cvtpk(st[kt][0],  st[kt][1]),
                                                    cvtpk(st[kt][4],  st[kt][5]),  0, 0);
        u32x2 a1 = __builtin_amdgcn_permlane32_swap(cvtpk(st[kt][2],  st[kt][3]),
                                                    cvtpk(st[kt][6],  st[kt][7]),  0, 0);
        u32x2 b0 = __builtin_amdgcn_permlane32_swap(cvtpk(st[kt][8],  st[kt][9]),
                                                    cvtpk(st[kt][12], st[kt][13]), 0, 0);
        u32x2 b1 = __builtin_amdgcn_permlane32_swap(cvtpk(st[kt][10], st[kt][11]),
                                                    cvtpk(st[kt][14], st[kt][15]), 0, 0);
        u32x4 w0 = { a0.x, a1.x, a0.y, a1.y };
        u32x4 w1 = { b0.x, b1.x, b0.y, b1.y };
        pfr[kt * 2]     = __builtin_bit_cast(bfrag, w0);
        pfr[kt * 2 + 1] = __builtin_bit_cast(bfrag, w1);
      }
      __builtin_amdgcn_s_setprio(1);
#pragma unroll
      for (int ks = 0; ks < 4; ++ks) {
        const char* vb = (const char*)Vs[cur] + l31 * 128 + ((ks * 32 + hi * 16) ^ sw);
#pragma unroll
        for (int dt = 0; dt < 4; ++dt) {
          bfrag vf = *(const bfrag*)(vb + dt * 4096);
          o[dt] = __builtin_amdgcn_mfma_f32_32x32x16_bf16(vf, pfr[ks], o[dt], 0, 0, 0);
        }
      }
      __builtin_amdgcn_s_setprio(0);
    }
    __syncthreads();
    if (pf) {
#pragma unroll
      for (int i = 0; i < 2; ++i) {
        *(s16x8*)((char*)Ks[cur ^ 1] + kldst[i]) = kr_[i];
        *(s16x8*)((char*)Vs[cur ^ 1] + vldst[i]) = vr_[i];
      }
    }
    __syncthreads();
  }
  const float linv = 1.f / l;
  short* aop = ao + (size_t)(b * 2048 + qg) * 4096 + h * 128 + 4 * hi;
#pragma unroll
  for (int dt = 0; dt < 4; ++dt)
#pragma unroll
    for (int r = 0; r < 16; ++r) {
      int d = dt * 32 + (r & 3) + 8 * (r >> 2);
      aop[d] = f2bf(o[dt][r] * linv);
    }
}

// ---------- launch ----------
extern "C" void kernel_launch(void* const* d_in, const int* in_sizes, int n_in,
                              void* d_out, int out_size, void* d_ws, size_t ws_size,
                              hipStream_t stream) {
  const float* x  = (const float*)d_in[0];
  const float* wq = (const float*)d_in[1];
  const float* wk = (const float*)d_in[2];
  const float* wv = (const float*)d_in[3];
  const float* wo = (const float*)d_in[4];
  const float* fc = (const float*)d_in[7];
  const float* fs = (const float*)d_in[8];

  char* ws = (char*)d_ws;
  short* xb    = (short*)(ws);                    // [4096][4096] bf16; reused as ao
  short* ao    = xb;
  short* wqkvb = (short*)(ws + 33554432ull);      // [6144][4096] bf16; reused as wob
  short* wob   = wqkvb;
  short* qkv   = (short*)(ws + 83886080ull);      // [4096][6144] bf16
  short* vt    = (short*)(ws + 134217728ull);     // [2][8][128][2048] bf16

  cvt_f32_bf16<<<16384, 256, 0, stream>>>(x,  xb,                 4194304);
  cvt_f32_bf16<<<16384, 256, 0, stream>>>(wq, wqkvb,              4194304);
  cvt_f32_bf16<<< 4096, 256, 0, stream>>>(wk, wqkvb + 16777216,   1048576);
  cvt_f32_bf16<<< 4096, 256, 0, stream>>>(wv, wqkvb + 20971520,   1048576);
  gemm128n<<<768, 512, 0, stream>>>(xb, wqkvb, qkv, 4096, 6144, 4096, 24);
  rope_k<<<4096, 256, 0, stream>>>(qkv, fc, fs);
  vtrans<<<dim3(32, 8, 2), 256, 0, stream>>>(qkv, vt);
  fattn2<<<dim3(8, 32, 2), 512, 0, stream>>>(qkv, vt, ao);
  cvt_f32_bf16<<<16384, 256, 0, stream>>>(wo, wob,                4194304);
  gemm256<false><<<256, 512, 0, stream>>>(ao, wob, (float*)d_out, 4096, 4096, 4096, 16);
}